// Round 3
// baseline (2469.480 us; speedup 1.0000x reference)
//
#include <hip/hip_runtime.h>

#define B_   16
#define C_   256
#define H_   48
#define W_   48
#define N_   (H_ * W_)   // 2304
#define KNN  8

#define TI 128
#define TJ 96
#define KC 16
#define JSPLIT 3
#define NTILES (N_ / TJ)        // 24
#define NJT (NTILES / JSPLIT)   // 8 j-tiles per block

// ---------------------------------------------------------------------------
// Kernel 1: transpose [B,C,N] -> [B,N,C]
// ---------------------------------------------------------------------------
__global__ __launch_bounds__(256) void k_transpose(const float* __restrict__ fm,
                                                   float* __restrict__ nodes) {
    __shared__ float tile[32][33];
    int b  = blockIdx.z;
    int n0 = blockIdx.x * 32;
    int c0 = blockIdx.y * 32;
    int tx = threadIdx.x;   // 0..31
    int ty = threadIdx.y;   // 0..7
    const float* src = fm + (size_t)b * C_ * N_;
    float* dst = nodes + (size_t)b * N_ * C_;
    #pragma unroll
    for (int cc = 0; cc < 32; cc += 8) {
        tile[cc + ty][tx] = src[(size_t)(c0 + cc + ty) * N_ + n0 + tx];
    }
    __syncthreads();
    #pragma unroll
    for (int nn = 0; nn < 32; nn += 8) {
        dst[(size_t)(n0 + nn + ty) * C_ + c0 + tx] = tile[tx][nn + ty];
    }
}

// ---------------------------------------------------------------------------
// Kernel 2: sq[b,n] = sum_c fm[b,c,n]^2
// ---------------------------------------------------------------------------
__global__ __launch_bounds__(256) void k_sq(const float* __restrict__ fm,
                                            float* __restrict__ sq) {
    int b = blockIdx.y;
    int n = blockIdx.x * 256 + threadIdx.x;
    const float* src = fm + (size_t)b * C_ * N_ + n;
    float s = 0.f;
    for (int c = 0; c < C_; ++c) {
        float v = src[(size_t)c * N_];
        s = fmaf(v, v, s);
    }
    sq[b * N_ + n] = s;
}

__device__ __forceinline__ bool lex_lt(float v, int i, float bv, int bi) {
    return (v < bv) || (v == bv && i < bi);
}

// ---------------------------------------------------------------------------
// Kernel 3: fused Gram + d2 + fully in-register running top-8.
// Block: 256 threads. Thread owns 4 rows x 12 cols per tile (acc[4][12]).
//   ti = tid>>3 (0..31) -> rows i0 + 4*ti .. +3
//   tj = tid&7  (0..7)  -> cols jg0 + 12*tj .. +11
// No d2 staging in LDS; selection state bestv/besti[4][8] in VGPRs.
// Per-block merge of the 8 col-strip lists -> partial top-8 per row -> pv/pi.
// ---------------------------------------------------------------------------
__global__ __launch_bounds__(256, 3) void k_knn(const float* __restrict__ nodes,
                                                const float* __restrict__ sq,
                                                float* __restrict__ pv,
                                                int* __restrict__ pi) {
    __shared__ __align__(16) float At[KC * TI];   // 8 KB  [k][row]
    __shared__ __align__(16) float Bt[KC * TJ];   // 6 KB  [k][col]
    __shared__ float sqj_s[TJ];

    int b   = blockIdx.z;
    int i0  = blockIdx.x * TI;
    int js  = blockIdx.y;
    int tid = threadIdx.x;
    const float* Xb = nodes + (size_t)b * N_ * C_;

    int ti = tid >> 3;            // 0..31
    int tj = tid & 7;             // 0..7
    int arow = tid >> 1, akoff = (tid & 1) * 8;   // A staging: 128 rows x 2 thr
    int brow = tid >> 1, bkoff = (tid & 1) * 8;   // B staging: valid tid<192

    float sqi[4];
    #pragma unroll
    for (int a = 0; a < 4; ++a) sqi[a] = sq[b * N_ + i0 + 4 * ti + a];

    float bestv[4][KNN];
    int   besti[4][KNN];
    #pragma unroll
    for (int a = 0; a < 4; ++a)
        #pragma unroll
        for (int q = 0; q < KNN; ++q) { bestv[a][q] = 3.4e38f; besti[a][q] = 0x7fffffff; }

    for (int jt = 0; jt < NJT; ++jt) {
        int jg0 = (js * NJT + jt) * TJ;
        __syncthreads();   // prev tile's finalize (sqj_s readers) done
        if (tid < TJ) sqj_s[tid] = sq[b * N_ + jg0 + tid];

        float acc[4][12];
        #pragma unroll
        for (int a = 0; a < 4; ++a)
            #pragma unroll
            for (int u = 0; u < 12; ++u) acc[a][u] = 0.f;

        for (int k0 = 0; k0 < C_; k0 += KC) {
            const float* ap = &Xb[(size_t)(i0 + arow) * C_ + k0 + akoff];
            float4 a0 = *(const float4*)ap;
            float4 a1 = *(const float4*)(ap + 4);
            float4 b0, b1;
            if (tid < 192) {
                const float* bp = &Xb[(size_t)(jg0 + brow) * C_ + k0 + bkoff];
                b0 = *(const float4*)bp;
                b1 = *(const float4*)(bp + 4);
            }
            __syncthreads();   // prev chunk's At/Bt reads done (covers sqj write too)
            At[(akoff + 0) * TI + arow] = a0.x; At[(akoff + 1) * TI + arow] = a0.y;
            At[(akoff + 2) * TI + arow] = a0.z; At[(akoff + 3) * TI + arow] = a0.w;
            At[(akoff + 4) * TI + arow] = a1.x; At[(akoff + 5) * TI + arow] = a1.y;
            At[(akoff + 6) * TI + arow] = a1.z; At[(akoff + 7) * TI + arow] = a1.w;
            if (tid < 192) {
                Bt[(bkoff + 0) * TJ + brow] = b0.x; Bt[(bkoff + 1) * TJ + brow] = b0.y;
                Bt[(bkoff + 2) * TJ + brow] = b0.z; Bt[(bkoff + 3) * TJ + brow] = b0.w;
                Bt[(bkoff + 4) * TJ + brow] = b1.x; Bt[(bkoff + 5) * TJ + brow] = b1.y;
                Bt[(bkoff + 6) * TJ + brow] = b1.z; Bt[(bkoff + 7) * TJ + brow] = b1.w;
            }
            __syncthreads();
            #pragma unroll
            for (int kk = 0; kk < KC; ++kk) {
                float4 a4  = *(const float4*)&At[kk * TI + 4 * ti];
                float4 bb0 = *(const float4*)&Bt[kk * TJ + 12 * tj];
                float4 bb1 = *(const float4*)&Bt[kk * TJ + 12 * tj + 4];
                float4 bb2 = *(const float4*)&Bt[kk * TJ + 12 * tj + 8];
                float aa[4]  = {a4.x, a4.y, a4.z, a4.w};
                float bv[12] = {bb0.x, bb0.y, bb0.z, bb0.w,
                                bb1.x, bb1.y, bb1.z, bb1.w,
                                bb2.x, bb2.y, bb2.z, bb2.w};
                #pragma unroll
                for (int a = 0; a < 4; ++a)
                    #pragma unroll
                    for (int u = 0; u < 12; ++u)
                        acc[a][u] = fmaf(aa[a], bv[u], acc[a][u]);
            }
        }

        // finalize tile: d2 + in-register insertion (ascending j, strict <)
        float sqjr[12];
        #pragma unroll
        for (int s = 0; s < 3; ++s) {
            float4 q4 = *(const float4*)&sqj_s[12 * tj + 4 * s];
            sqjr[4 * s + 0] = q4.x; sqjr[4 * s + 1] = q4.y;
            sqjr[4 * s + 2] = q4.z; sqjr[4 * s + 3] = q4.w;
        }
        #pragma unroll
        for (int a = 0; a < 4; ++a) {
            int gi = i0 + 4 * ti + a;
            #pragma unroll
            for (int u = 0; u < 12; ++u) {
                int gj = jg0 + 12 * tj + u;
                float d2 = sqi[a] + sqjr[u] - 2.f * acc[a][u];
                if (gi == gj) d2 = 1e30f;
                if (d2 < bestv[a][KNN - 1]) {
                    float cv = d2; int ci = gj;
                    #pragma unroll
                    for (int p = 0; p < KNN; ++p) {
                        if (cv < bestv[a][p]) {
                            float tv = bestv[a][p]; bestv[a][p] = cv; cv = tv;
                            int tx2 = besti[a][p]; besti[a][p] = ci; ci = tx2;
                        }
                    }
                }
            }
        }
    }

    // ---- per-block merge: 8 chunks of 16 rows, via reused At/Bt ----
    float* mv_s = At;          // [16 rows][8 tj][8]
    int*   mi_s = (int*)Bt;    // [16 rows][8 tj][8]  (1024 ints <= 1536)
    for (int c = 0; c < 8; ++c) {
        __syncthreads();
        if ((tid >> 5) == c) {           // ti in [4c, 4c+4) -> rows 16c..16c+15
            int lr4 = (ti & 3) * 4;
            #pragma unroll
            for (int a = 0; a < 4; ++a)
                #pragma unroll
                for (int q = 0; q < KNN; ++q) {
                    mv_s[(lr4 + a) * 64 + tj * 8 + q] = bestv[a][q];
                    mi_s[(lr4 + a) * 64 + tj * 8 + q] = besti[a][q];
                }
        }
        __syncthreads();
        if (tid < 16) {
            float mv[KNN]; int mi[KNN];
            #pragma unroll
            for (int q = 0; q < KNN; ++q) { mv[q] = 3.4e38f; mi[q] = 0x7fffffff; }
            for (int s = 0; s < 64; ++s) {
                float v = mv_s[tid * 64 + s]; int ix = mi_s[tid * 64 + s];
                if (lex_lt(v, ix, mv[KNN - 1], mi[KNN - 1])) {
                    float cv = v; int ci = ix;
                    #pragma unroll
                    for (int p = 0; p < KNN; ++p) {
                        if (lex_lt(cv, ci, mv[p], mi[p])) {
                            float tv = mv[p]; mv[p] = cv; cv = tv;
                            int tx2 = mi[p]; mi[p] = ci; ci = tx2;
                        }
                    }
                }
            }
            int row = i0 + c * 16 + tid;
            size_t base = (((size_t)b * N_ + row) * JSPLIT + js) * KNN;
            #pragma unroll
            for (int q = 0; q < KNN; ++q) { pv[base + q] = mv[q]; pi[base + q] = mi[q]; }
        }
    }
}

// ---------------------------------------------------------------------------
// Kernel 3b: merge JSPLIT partial top-8 lists per row -> final knn indices
// ---------------------------------------------------------------------------
__global__ __launch_bounds__(256) void k_merge(const float* __restrict__ pv,
                                               const int* __restrict__ pi,
                                               int* __restrict__ knn) {
    int t = blockIdx.x * 256 + threadIdx.x;   // row id b*N+i (36864 = 144*256)
    float mv[KNN]; int mi[KNN];
    #pragma unroll
    for (int k = 0; k < KNN; ++k) { mv[k] = 3.4e38f; mi[k] = 0x7fffffff; }
    const float* v  = pv + (size_t)t * JSPLIT * KNN;
    const int*   ix = pi + (size_t)t * JSPLIT * KNN;
    for (int s = 0; s < JSPLIT * KNN; ++s) {
        float cv = v[s]; int ci = ix[s];
        if (lex_lt(cv, ci, mv[KNN - 1], mi[KNN - 1])) {
            #pragma unroll
            for (int p = 0; p < KNN; ++p) {
                if (lex_lt(cv, ci, mv[p], mi[p])) {
                    float tv = mv[p]; mv[p] = cv; cv = tv;
                    int tx2 = mi[p]; mi[p] = ci; ci = tx2;
                }
            }
        }
    }
    int* kr = knn + (size_t)t * KNN;
    #pragma unroll
    for (int q = 0; q < KNN; ++q) kr[q] = mi[q];
}

// ---------------------------------------------------------------------------
// Kernel 4: aggregate (grid 4-nbrs + 8 knn) mean + residual + LayerNorm(C)
//           + transposed write-out to [B,C,N]
// ---------------------------------------------------------------------------
__global__ __launch_bounds__(256) void k_agg_ln(const float* __restrict__ nodes,
                                                const int* __restrict__ knn,
                                                const float* __restrict__ gamma,
                                                const float* __restrict__ beta,
                                                float* __restrict__ out) {
    __shared__ float ytile[16][C_ + 1];
    __shared__ float red[8];

    int b   = blockIdx.y;
    int i0  = blockIdx.x * 16;
    int tid = threadIdx.x;   // channel c
    const float* Xb = nodes + (size_t)b * N_ * C_;
    float g  = gamma[tid];
    float be = beta[tid];

    for (int ii = 0; ii < 16; ++ii) {
        int i  = i0 + ii;
        int x_ = i % W_;
        int y_ = i / W_;
        float s = 0.f;
        int cnt = KNN;
        if (x_ > 0)      { s += Xb[(size_t)(i - 1)  * C_ + tid]; cnt++; }
        if (x_ < W_ - 1) { s += Xb[(size_t)(i + 1)  * C_ + tid]; cnt++; }
        if (y_ > 0)      { s += Xb[(size_t)(i - W_) * C_ + tid]; cnt++; }
        if (y_ < H_ - 1) { s += Xb[(size_t)(i + W_) * C_ + tid]; cnt++; }
        const int* kr = knn + ((size_t)b * N_ + i) * KNN;
        #pragma unroll
        for (int k = 0; k < KNN; ++k) s += Xb[(size_t)kr[k] * C_ + tid];

        float yv = s / (float)cnt + Xb[(size_t)i * C_ + tid];

        float rx = yv, ry = yv * yv;
        #pragma unroll
        for (int m = 32; m >= 1; m >>= 1) {
            rx += __shfl_xor(rx, m);
            ry += __shfl_xor(ry, m);
        }
        int wid = tid >> 6, lane = tid & 63;
        __syncthreads();
        if (lane == 0) { red[wid * 2] = rx; red[wid * 2 + 1] = ry; }
        __syncthreads();
        float S1 = red[0] + red[2] + red[4] + red[6];
        float S2 = red[1] + red[3] + red[5] + red[7];
        float mu  = S1 * (1.f / C_);
        float var = S2 * (1.f / C_) - mu * mu;
        float inv = rsqrtf(var + 1e-5f);
        ytile[ii][tid] = (yv - mu) * inv * g + be;
    }
    __syncthreads();

    float* op = out + (size_t)b * C_ * N_ + (size_t)tid * N_ + i0;
    float vv[16];
    #pragma unroll
    for (int ii = 0; ii < 16; ++ii) vv[ii] = ytile[ii][tid];
    #pragma unroll
    for (int q = 0; q < 4; ++q) {
        float4 w;
        w.x = vv[q * 4 + 0]; w.y = vv[q * 4 + 1];
        w.z = vv[q * 4 + 2]; w.w = vv[q * 4 + 3];
        *(float4*)&op[q * 4] = w;
    }
}

// ---------------------------------------------------------------------------
extern "C" void kernel_launch(void* const* d_in, const int* in_sizes, int n_in,
                              void* d_out, int out_size, void* d_ws, size_t ws_size,
                              hipStream_t stream) {
    const float* fm    = (const float*)d_in[0];
    const float* gamma = (const float*)d_in[1];
    const float* beta  = (const float*)d_in[2];
    float* out = (float*)d_out;

    char* ws = (char*)d_ws;
    size_t off = 0;
    float* nodes = (float*)(ws + off); off += (size_t)B_ * N_ * C_ * sizeof(float);          // 37.75 MB
    float* sq    = (float*)(ws + off); off += (size_t)B_ * N_ * sizeof(float);               // 0.14 MB
    int*   knn   = (int*)  (ws + off); off += (size_t)B_ * N_ * KNN * sizeof(int);           // 1.18 MB
    float* pv    = (float*)(ws + off); off += (size_t)B_ * N_ * JSPLIT * KNN * sizeof(float);// 3.5 MB
    int*   pi    = (int*)  (ws + off); off += (size_t)B_ * N_ * JSPLIT * KNN * sizeof(int);  // 3.5 MB

    k_transpose<<<dim3(N_ / 32, C_ / 32, B_), dim3(32, 8), 0, stream>>>(fm, nodes);
    k_sq<<<dim3(N_ / 256, B_), 256, 0, stream>>>(fm, sq);
    k_knn<<<dim3(N_ / TI, JSPLIT, B_), 256, 0, stream>>>(nodes, sq, pv, pi);
    k_merge<<<(B_ * N_) / 256, 256, 0, stream>>>(pv, pi, knn);
    k_agg_ln<<<dim3(N_ / 16, B_), 256, 0, stream>>>(nodes, knn, gamma, beta, out);
}

// Round 4
// 2439.691 us; speedup vs baseline: 1.0122x; 1.0122x over previous
//
#include <hip/hip_runtime.h>

#define B_   16
#define C_   256
#define H_   48
#define W_   48
#define N_   (H_ * W_)   // 2304
#define KNN  8

#define TI 128
#define TJ 64
#define KC 32
#define JSPLIT 4
#define NJT (N_ / TJ / JSPLIT)   // 9 j-tiles per block

// ---------------------------------------------------------------------------
// Kernel 1: transpose [B,C,N] -> [B,N,C]
// ---------------------------------------------------------------------------
__global__ __launch_bounds__(256) void k_transpose(const float* __restrict__ fm,
                                                   float* __restrict__ nodes) {
    __shared__ float tile[32][33];
    int b  = blockIdx.z;
    int n0 = blockIdx.x * 32;
    int c0 = blockIdx.y * 32;
    int tx = threadIdx.x;   // 0..31
    int ty = threadIdx.y;   // 0..7
    const float* src = fm + (size_t)b * C_ * N_;
    float* dst = nodes + (size_t)b * N_ * C_;
    #pragma unroll
    for (int cc = 0; cc < 32; cc += 8) {
        tile[cc + ty][tx] = src[(size_t)(c0 + cc + ty) * N_ + n0 + tx];
    }
    __syncthreads();
    #pragma unroll
    for (int nn = 0; nn < 32; nn += 8) {
        dst[(size_t)(n0 + nn + ty) * C_ + c0 + tx] = tile[tx][nn + ty];
    }
}

// ---------------------------------------------------------------------------
// Kernel 2: sq[b,n] = sum_c fm[b,c,n]^2
// ---------------------------------------------------------------------------
__global__ __launch_bounds__(256) void k_sq(const float* __restrict__ fm,
                                            float* __restrict__ sq) {
    int b = blockIdx.y;
    int n = blockIdx.x * 256 + threadIdx.x;
    const float* src = fm + (size_t)b * C_ * N_ + n;
    float s = 0.f;
    for (int c = 0; c < C_; ++c) {
        float v = src[(size_t)c * N_];
        s = fmaf(v, v, s);
    }
    sq[b * N_ + n] = s;
}

__device__ __forceinline__ bool lex_lt(float v, int i, float bv, int bi) {
    return (v < bv) || (v == bv && i < bi);
}

// ---------------------------------------------------------------------------
// Kernel 3: fused Gram + d2 + in-register running top-8.
// Thread owns 4 rows x 8 cols (acc[4][8]).  ti = tid>>3 (0..31), tj = tid&7.
// KC=32 k-chunks, register prefetch of next chunk overlapped with FMAs.
// Plain launch_bounds(256): DO NOT add a min-occupancy arg (round-3 spill).
// ---------------------------------------------------------------------------
__global__ __launch_bounds__(256) void k_knn(const float* __restrict__ nodes,
                                             const float* __restrict__ sq,
                                             float* __restrict__ pv,
                                             int* __restrict__ pi) {
    __shared__ __align__(16) float At[KC * TI];   // 16 KB [k][row]
    __shared__ __align__(16) float Bt[KC * TJ];   // 8 KB  [k][col]

    int b   = blockIdx.z;
    int i0  = blockIdx.x * TI;
    int js  = blockIdx.y;
    int tid = threadIdx.x;
    const float* Xb  = nodes + (size_t)b * N_ * C_;
    const float* sqb = sq + b * N_;

    int ti = tid >> 3;            // 0..31 -> rows i0 + 4*ti .. +3
    int tj = tid & 7;             // 0..7  -> cols jg0 + 8*tj .. +7
    int arow = tid >> 1, akoff = (tid & 1) * 16;  // A: 128r x 32k, 16 f/thread
    int brow = tid >> 2, bkoff = (tid & 3) * 8;   // B:  64r x 32k,  8 f/thread

    float sqi[4];
    #pragma unroll
    for (int a = 0; a < 4; ++a) sqi[a] = sqb[i0 + 4 * ti + a];

    float bestv[4][KNN];
    int   besti[4][KNN];
    #pragma unroll
    for (int a = 0; a < 4; ++a)
        #pragma unroll
        for (int q = 0; q < KNN; ++q) { bestv[a][q] = 3.4e38f; besti[a][q] = 0x7fffffff; }

    for (int jt = 0; jt < NJT; ++jt) {
        int jg0 = (js * NJT + jt) * TJ;

        float acc[4][8];
        #pragma unroll
        for (int a = 0; a < 4; ++a)
            #pragma unroll
            for (int u = 0; u < 8; ++u) acc[a][u] = 0.f;

        // prefetch chunk 0 into regs
        const float* ap = &Xb[(size_t)(i0 + arow) * C_ + akoff];
        const float* bp = &Xb[(size_t)(jg0 + brow) * C_ + bkoff];
        float4 a0 = *(const float4*)(ap + 0);
        float4 a1 = *(const float4*)(ap + 4);
        float4 a2 = *(const float4*)(ap + 8);
        float4 a3 = *(const float4*)(ap + 12);
        float4 b0 = *(const float4*)(bp + 0);
        float4 b1 = *(const float4*)(bp + 4);

        for (int k0 = 0; k0 < C_; k0 += KC) {
            __syncthreads();   // previous chunk's LDS reads done
            At[(akoff +  0) * TI + arow] = a0.x; At[(akoff +  1) * TI + arow] = a0.y;
            At[(akoff +  2) * TI + arow] = a0.z; At[(akoff +  3) * TI + arow] = a0.w;
            At[(akoff +  4) * TI + arow] = a1.x; At[(akoff +  5) * TI + arow] = a1.y;
            At[(akoff +  6) * TI + arow] = a1.z; At[(akoff +  7) * TI + arow] = a1.w;
            At[(akoff +  8) * TI + arow] = a2.x; At[(akoff +  9) * TI + arow] = a2.y;
            At[(akoff + 10) * TI + arow] = a2.z; At[(akoff + 11) * TI + arow] = a2.w;
            At[(akoff + 12) * TI + arow] = a3.x; At[(akoff + 13) * TI + arow] = a3.y;
            At[(akoff + 14) * TI + arow] = a3.z; At[(akoff + 15) * TI + arow] = a3.w;
            Bt[(bkoff + 0) * TJ + brow] = b0.x; Bt[(bkoff + 1) * TJ + brow] = b0.y;
            Bt[(bkoff + 2) * TJ + brow] = b0.z; Bt[(bkoff + 3) * TJ + brow] = b0.w;
            Bt[(bkoff + 4) * TJ + brow] = b1.x; Bt[(bkoff + 5) * TJ + brow] = b1.y;
            Bt[(bkoff + 6) * TJ + brow] = b1.z; Bt[(bkoff + 7) * TJ + brow] = b1.w;
            __syncthreads();

            if (k0 + KC < C_) {   // prefetch next chunk during compute
                a0 = *(const float4*)(ap + k0 + KC + 0);
                a1 = *(const float4*)(ap + k0 + KC + 4);
                a2 = *(const float4*)(ap + k0 + KC + 8);
                a3 = *(const float4*)(ap + k0 + KC + 12);
                b0 = *(const float4*)(bp + k0 + KC + 0);
                b1 = *(const float4*)(bp + k0 + KC + 4);
            }

            #pragma unroll
            for (int kk = 0; kk < KC; ++kk) {
                float4 a4  = *(const float4*)&At[kk * TI + 4 * ti];
                float4 bb0 = *(const float4*)&Bt[kk * TJ + 8 * tj];
                float4 bb1 = *(const float4*)&Bt[kk * TJ + 8 * tj + 4];
                float aa[4] = {a4.x, a4.y, a4.z, a4.w};
                float bv[8] = {bb0.x, bb0.y, bb0.z, bb0.w, bb1.x, bb1.y, bb1.z, bb1.w};
                #pragma unroll
                for (int a = 0; a < 4; ++a)
                    #pragma unroll
                    for (int u = 0; u < 8; ++u)
                        acc[a][u] = fmaf(aa[a], bv[u], acc[a][u]);
            }
        }

        // finalize tile: d2 + in-register insertion (ascending j, strict <)
        float sqjr[8];
        {
            float4 q0 = *(const float4*)&sqb[jg0 + 8 * tj];
            float4 q1 = *(const float4*)&sqb[jg0 + 8 * tj + 4];
            sqjr[0] = q0.x; sqjr[1] = q0.y; sqjr[2] = q0.z; sqjr[3] = q0.w;
            sqjr[4] = q1.x; sqjr[5] = q1.y; sqjr[6] = q1.z; sqjr[7] = q1.w;
        }
        #pragma unroll
        for (int a = 0; a < 4; ++a) {
            int gi = i0 + 4 * ti + a;
            #pragma unroll
            for (int u = 0; u < 8; ++u) {
                int gj = jg0 + 8 * tj + u;
                float d2 = sqi[a] + sqjr[u] - 2.f * acc[a][u];
                if (gi == gj) d2 = 1e30f;
                if (d2 < bestv[a][KNN - 1]) {
                    float cv = d2; int ci = gj;
                    #pragma unroll
                    for (int p = 0; p < KNN; ++p) {
                        if (cv < bestv[a][p]) {
                            float tv = bestv[a][p]; bestv[a][p] = cv; cv = tv;
                            int tx2 = besti[a][p]; besti[a][p] = ci; ci = tx2;
                        }
                    }
                }
            }
        }
    }

    // ---- per-block merge: 8 chunks of 16 rows, via reused At/Bt ----
    float* mv_s = At;          // [16 rows][8 tj][8] floats
    int*   mi_s = (int*)Bt;    // [16 rows][8 tj][8] ints
    for (int c = 0; c < 8; ++c) {
        __syncthreads();
        if ((tid >> 5) == c) {           // ti in [4c,4c+4) -> rows 16c..16c+15
            int lr4 = (ti & 3) * 4;
            #pragma unroll
            for (int a = 0; a < 4; ++a)
                #pragma unroll
                for (int q = 0; q < KNN; ++q) {
                    mv_s[(lr4 + a) * 64 + tj * 8 + q] = bestv[a][q];
                    mi_s[(lr4 + a) * 64 + tj * 8 + q] = besti[a][q];
                }
        }
        __syncthreads();
        if (tid < 16) {
            float mv[KNN]; int mi[KNN];
            #pragma unroll
            for (int q = 0; q < KNN; ++q) { mv[q] = 3.4e38f; mi[q] = 0x7fffffff; }
            for (int s = 0; s < 64; ++s) {
                float v = mv_s[tid * 64 + s]; int ix = mi_s[tid * 64 + s];
                if (lex_lt(v, ix, mv[KNN - 1], mi[KNN - 1])) {
                    float cv = v; int ci = ix;
                    #pragma unroll
                    for (int p = 0; p < KNN; ++p) {
                        if (lex_lt(cv, ci, mv[p], mi[p])) {
                            float tv = mv[p]; mv[p] = cv; cv = tv;
                            int tx2 = mi[p]; mi[p] = ci; ci = tx2;
                        }
                    }
                }
            }
            int row = i0 + c * 16 + tid;
            size_t base = (((size_t)b * N_ + row) * JSPLIT + js) * KNN;
            #pragma unroll
            for (int q = 0; q < KNN; ++q) { pv[base + q] = mv[q]; pi[base + q] = mi[q]; }
        }
    }
}

// ---------------------------------------------------------------------------
// Kernel 3b: merge JSPLIT partial top-8 lists per row -> final knn indices
// ---------------------------------------------------------------------------
__global__ __launch_bounds__(256) void k_merge(const float* __restrict__ pv,
                                               const int* __restrict__ pi,
                                               int* __restrict__ knn) {
    int t = blockIdx.x * 256 + threadIdx.x;   // row id b*N+i (36864 = 144*256)
    float mv[KNN]; int mi[KNN];
    #pragma unroll
    for (int k = 0; k < KNN; ++k) { mv[k] = 3.4e38f; mi[k] = 0x7fffffff; }
    const float* v  = pv + (size_t)t * JSPLIT * KNN;
    const int*   ix = pi + (size_t)t * JSPLIT * KNN;
    for (int s = 0; s < JSPLIT * KNN; ++s) {
        float cv = v[s]; int ci = ix[s];
        if (lex_lt(cv, ci, mv[KNN - 1], mi[KNN - 1])) {
            #pragma unroll
            for (int p = 0; p < KNN; ++p) {
                if (lex_lt(cv, ci, mv[p], mi[p])) {
                    float tv = mv[p]; mv[p] = cv; cv = tv;
                    int tx2 = mi[p]; mi[p] = ci; ci = tx2;
                }
            }
        }
    }
    int* kr = knn + (size_t)t * KNN;
    #pragma unroll
    for (int q = 0; q < KNN; ++q) kr[q] = mi[q];
}

// ---------------------------------------------------------------------------
// Kernel 4: aggregate (grid 4-nbrs + 8 knn) mean + residual + LayerNorm(C)
//           + transposed write-out to [B,C,N]
// ---------------------------------------------------------------------------
__global__ __launch_bounds__(256) void k_agg_ln(const float* __restrict__ nodes,
                                                const int* __restrict__ knn,
                                                const float* __restrict__ gamma,
                                                const float* __restrict__ beta,
                                                float* __restrict__ out) {
    __shared__ float ytile[16][C_ + 1];
    __shared__ float red[8];

    int b   = blockIdx.y;
    int i0  = blockIdx.x * 16;
    int tid = threadIdx.x;   // channel c
    const float* Xb = nodes + (size_t)b * N_ * C_;
    float g  = gamma[tid];
    float be = beta[tid];

    for (int ii = 0; ii < 16; ++ii) {
        int i  = i0 + ii;
        int x_ = i % W_;
        int y_ = i / W_;
        float s = 0.f;
        int cnt = KNN;
        if (x_ > 0)      { s += Xb[(size_t)(i - 1)  * C_ + tid]; cnt++; }
        if (x_ < W_ - 1) { s += Xb[(size_t)(i + 1)  * C_ + tid]; cnt++; }
        if (y_ > 0)      { s += Xb[(size_t)(i - W_) * C_ + tid]; cnt++; }
        if (y_ < H_ - 1) { s += Xb[(size_t)(i + W_) * C_ + tid]; cnt++; }
        const int* kr = knn + ((size_t)b * N_ + i) * KNN;
        #pragma unroll
        for (int k = 0; k < KNN; ++k) s += Xb[(size_t)kr[k] * C_ + tid];

        float yv = s / (float)cnt + Xb[(size_t)i * C_ + tid];

        float rx = yv, ry = yv * yv;
        #pragma unroll
        for (int m = 32; m >= 1; m >>= 1) {
            rx += __shfl_xor(rx, m);
            ry += __shfl_xor(ry, m);
        }
        int wid = tid >> 6, lane = tid & 63;
        __syncthreads();
        if (lane == 0) { red[wid * 2] = rx; red[wid * 2 + 1] = ry; }
        __syncthreads();
        float S1 = red[0] + red[2] + red[4] + red[6];
        float S2 = red[1] + red[3] + red[5] + red[7];
        float mu  = S1 * (1.f / C_);
        float var = S2 * (1.f / C_) - mu * mu;
        float inv = rsqrtf(var + 1e-5f);
        ytile[ii][tid] = (yv - mu) * inv * g + be;
    }
    __syncthreads();

    float* op = out + (size_t)b * C_ * N_ + (size_t)tid * N_ + i0;
    float vv[16];
    #pragma unroll
    for (int ii = 0; ii < 16; ++ii) vv[ii] = ytile[ii][tid];
    #pragma unroll
    for (int q = 0; q < 4; ++q) {
        float4 w;
        w.x = vv[q * 4 + 0]; w.y = vv[q * 4 + 1];
        w.z = vv[q * 4 + 2]; w.w = vv[q * 4 + 3];
        *(float4*)&op[q * 4] = w;
    }
}

// ---------------------------------------------------------------------------
extern "C" void kernel_launch(void* const* d_in, const int* in_sizes, int n_in,
                              void* d_out, int out_size, void* d_ws, size_t ws_size,
                              hipStream_t stream) {
    const float* fm    = (const float*)d_in[0];
    const float* gamma = (const float*)d_in[1];
    const float* beta  = (const float*)d_in[2];
    float* out = (float*)d_out;

    char* ws = (char*)d_ws;
    size_t off = 0;
    float* nodes = (float*)(ws + off); off += (size_t)B_ * N_ * C_ * sizeof(float);          // 37.75 MB
    float* sq    = (float*)(ws + off); off += (size_t)B_ * N_ * sizeof(float);               // 0.14 MB
    int*   knn   = (int*)  (ws + off); off += (size_t)B_ * N_ * KNN * sizeof(int);           // 1.18 MB
    float* pv    = (float*)(ws + off); off += (size_t)B_ * N_ * JSPLIT * KNN * sizeof(float);// 4.7 MB
    int*   pi    = (int*)  (ws + off); off += (size_t)B_ * N_ * JSPLIT * KNN * sizeof(int);  // 4.7 MB

    k_transpose<<<dim3(N_ / 32, C_ / 32, B_), dim3(32, 8), 0, stream>>>(fm, nodes);
    k_sq<<<dim3(N_ / 256, B_), 256, 0, stream>>>(fm, sq);
    k_knn<<<dim3(N_ / TI, JSPLIT, B_), 256, 0, stream>>>(nodes, sq, pv, pi);
    k_merge<<<(B_ * N_) / 256, 256, 0, stream>>>(pv, pi, knn);
    k_agg_ln<<<dim3(N_ / 16, B_), 256, 0, stream>>>(nodes, knn, gamma, beta, out);
}

// Round 5
// 964.191 us; speedup vs baseline: 2.5612x; 2.5303x over previous
//
#include <hip/hip_runtime.h>

#define B_   16
#define C_   256
#define H_   48
#define W_   48
#define N_   (H_ * W_)   // 2304
#define KNN  8

#define KA   288          // padded bf16 row: 256 data + e1,e2 + zeros (16B*36 granules)
#define MPRE 10           // prefilter list depth per j-subset
#define JSPLIT 2

typedef __attribute__((ext_vector_type(8)))  short bf16x8;
typedef __attribute__((ext_vector_type(8)))  unsigned short u16x8;
typedef __attribute__((ext_vector_type(16))) float f32x16;

__device__ __forceinline__ unsigned short f2bf(float f) {
    unsigned int u = __float_as_uint(f);
    u = (u + 0x7FFF + ((u >> 16) & 1)) >> 16;   // RNE
    return (unsigned short)u;
}
__device__ __forceinline__ float bf2f(unsigned short h) {
    return __uint_as_float(((unsigned int)h) << 16);
}
__device__ __forceinline__ bool lex_lt(float v, int i, float bv, int bi) {
    return (v < bv) || (v == bv && i < bi);
}
__device__ __forceinline__ bool lex_gt(float v, int i, float bv, int bi) {
    return (v > bv) || (v == bv && i < bi);
}

// ---------------------------------------------------------------------------
// Kernel 1: transpose [B,C,N] -> [B,N,C]
// ---------------------------------------------------------------------------
__global__ __launch_bounds__(256) void k_transpose(const float* __restrict__ fm,
                                                   float* __restrict__ nodes) {
    __shared__ float tile[32][33];
    int b  = blockIdx.z;
    int n0 = blockIdx.x * 32;
    int c0 = blockIdx.y * 32;
    int tx = threadIdx.x, ty = threadIdx.y;
    const float* src = fm + (size_t)b * C_ * N_;
    float* dst = nodes + (size_t)b * N_ * C_;
    #pragma unroll
    for (int cc = 0; cc < 32; cc += 8)
        tile[cc + ty][tx] = src[(size_t)(c0 + cc + ty) * N_ + n0 + tx];
    __syncthreads();
    #pragma unroll
    for (int nn = 0; nn < 32; nn += 8)
        dst[(size_t)(n0 + nn + ty) * C_ + c0 + tx] = tile[tx][nn + ty];
}

// ---------------------------------------------------------------------------
// Kernel 2: sq[b,n] = sum_c fm[b,c,n]^2
// ---------------------------------------------------------------------------
__global__ __launch_bounds__(256) void k_sq(const float* __restrict__ fm,
                                            float* __restrict__ sq) {
    int b = blockIdx.y;
    int n = blockIdx.x * 256 + threadIdx.x;
    const float* src = fm + (size_t)b * C_ * N_ + n;
    float s = 0.f;
    for (int c = 0; c < C_; ++c) { float v = src[(size_t)c * N_]; s = fmaf(v, v, s); }
    sq[b * N_ + n] = s;
}

// ---------------------------------------------------------------------------
// Kernel 3: build augmented bf16 matrix Xa[b][n][KA]:
//   k<256: bf16(X);  k=256: e1=bf16(-sq/2);  k=257: e2=bf16(-sq/2 - e1); else 0
// One thread per 16B granule (36 per row).
// ---------------------------------------------------------------------------
__global__ __launch_bounds__(256) void k_convert(const float* __restrict__ nodes,
                                                 const float* __restrict__ sq,
                                                 unsigned short* __restrict__ Xa) {
    int idx = blockIdx.x * 256 + threadIdx.x;   // 36864 rows * 36 granules
    int r = idx / 36, g = idx - r * 36;
    u16x8 o = (u16x8){0, 0, 0, 0, 0, 0, 0, 0};
    if (g < 32) {
        const float* src = nodes + (size_t)r * C_ + g * 8;
        float4 f0 = *(const float4*)(src);
        float4 f1 = *(const float4*)(src + 4);
        o[0] = f2bf(f0.x); o[1] = f2bf(f0.y); o[2] = f2bf(f0.z); o[3] = f2bf(f0.w);
        o[4] = f2bf(f1.x); o[5] = f2bf(f1.y); o[6] = f2bf(f1.z); o[7] = f2bf(f1.w);
    } else if (g == 32) {
        float s  = -0.5f * sq[r];
        unsigned short e1 = f2bf(s);
        unsigned short e2 = f2bf(s - bf2f(e1));
        o[0] = e1; o[1] = e2;
    }
    *(u16x8*)(Xa + (size_t)r * KA + g * 8) = o;
}

// ---------------------------------------------------------------------------
// Kernel 4: MFMA prefilter.
// Block: 256 thr = 4 waves (wj = wave&1 -> j-sub 32 of the 64-j tile,
//                           wi = wave>>1 -> i-sub 64 of the 128-i block).
// S'[j][i] = dot(Xj,Xi) - sqj/2 via augmented K=272 (17 MFMA steps).
// i-side fragments resident in registers; A streams from global (L1/L2).
// Lane owns i = i_base + ig*32 + (lane&31); per-lane top-MPRE (desc S', tie
// smaller j; j visited ascending within each (wj,half) subset).
// In-block LDS merge of the 4 subset lists -> pi_pre[b][i][js][MPRE].
// ---------------------------------------------------------------------------
__global__ __launch_bounds__(256) void k_knn_mfma(const unsigned short* __restrict__ Xa,
                                                  int* __restrict__ pi_pre) {
    __shared__ float mv_s[2][32][2][2][MPRE];   // [wi][col][wj][half][q]
    __shared__ int   mi_s[2][32][2][2][MPRE];

    int b   = blockIdx.z;
    int i0  = blockIdx.x * 128;
    int js  = blockIdx.y;
    int tid = threadIdx.x;
    int wave = tid >> 6, lane = tid & 63;
    int wj = wave & 1, wi = wave >> 1;
    int l31 = lane & 31, lh = lane >> 5;

    const unsigned short* Xb = Xa + (size_t)b * N_ * KA;
    int i_base = i0 + wi * 64;

    // resident i-side fragments (t = 0..15)
    bf16x8 bfr0[16], bfr1[16];
    const unsigned short* ib0 = Xb + (size_t)(i_base + l31) * KA + lh * 8;
    const unsigned short* ib1 = ib0 + (size_t)32 * KA;
    #pragma unroll
    for (int t = 0; t < 16; ++t) {
        bfr0[t] = *(const bf16x8*)(ib0 + t * 16);
        bfr1[t] = *(const bf16x8*)(ib1 + t * 16);
    }
    // constant i-side frag for t=16: [1,1,0,...] at k=256,257 (lanes<32 only)
    short one = (lh == 0) ? (short)0x3F80 : (short)0;
    bf16x8 bc = (bf16x8){one, one, 0, 0, 0, 0, 0, 0};

    int I0 = i_base + l31, I1 = I0 + 32;

    float bv0[MPRE], bv1[MPRE];
    int   bi0[MPRE], bi1[MPRE];
    #pragma unroll
    for (int q = 0; q < MPRE; ++q) {
        bv0[q] = -3.4e38f; bv1[q] = -3.4e38f;
        bi0[q] = 0x7fffffff; bi1[q] = 0x7fffffff;
    }

    for (int jt = 0; jt < 18; ++jt) {
        int j0 = js * (N_ / JSPLIT) + jt * 64 + wj * 32;
        const unsigned short* ab = Xb + (size_t)(j0 + l31) * KA + lh * 8;

        f32x16 acc0, acc1;
        #pragma unroll
        for (int r = 0; r < 16; ++r) { acc0[r] = 0.f; acc1[r] = 0.f; }

        #pragma unroll
        for (int t = 0; t < 16; ++t) {
            bf16x8 af = *(const bf16x8*)(ab + t * 16);
            acc0 = __builtin_amdgcn_mfma_f32_32x32x16_bf16(af, bfr0[t], acc0, 0, 0, 0);
            acc1 = __builtin_amdgcn_mfma_f32_32x32x16_bf16(af, bfr1[t], acc1, 0, 0, 0);
        }
        {   // t=16: k 256..271 (A has [e1,e2,0..]; B is the constant ones-frag)
            bf16x8 af = *(const bf16x8*)(ab + 256);
            acc0 = __builtin_amdgcn_mfma_f32_32x32x16_bf16(af, bc, acc0, 0, 0, 0);
            acc1 = __builtin_amdgcn_mfma_f32_32x32x16_bf16(af, bc, acc1, 0, 0, 0);
        }

        // selection: j rows ascend with r ((r&3)+8*(r>>2)); strict > keeps smaller j on ties
        #pragma unroll
        for (int r = 0; r < 16; ++r) {
            int gj = j0 + (r & 3) + 8 * (r >> 2) + 4 * lh;
            float v0 = (gj == I0) ? -3.4e38f : acc0[r];
            if (v0 > bv0[MPRE - 1]) {
                float cv = v0; int ci = gj;
                #pragma unroll
                for (int p = 0; p < MPRE; ++p) {
                    if (cv > bv0[p]) {
                        float tv = bv0[p]; bv0[p] = cv; cv = tv;
                        int tx2 = bi0[p]; bi0[p] = ci; ci = tx2;
                    }
                }
            }
            float v1 = (gj == I1) ? -3.4e38f : acc1[r];
            if (v1 > bv1[MPRE - 1]) {
                float cv = v1; int ci = gj;
                #pragma unroll
                for (int p = 0; p < MPRE; ++p) {
                    if (cv > bv1[p]) {
                        float tv = bv1[p]; bv1[p] = cv; cv = tv;
                        int tx2 = bi1[p]; bi1[p] = ci; ci = tx2;
                    }
                }
            }
        }
    }

    // merge the 4 subset lists per i (wj x half) -> top-MPRE -> pi_pre
    #pragma unroll
    for (int ig = 0; ig < 2; ++ig) {
        __syncthreads();
        #pragma unroll
        for (int q = 0; q < MPRE; ++q) {
            mv_s[wi][l31][wj][lh][q] = (ig == 0) ? bv0[q] : bv1[q];
            mi_s[wi][l31][wj][lh][q] = (ig == 0) ? bi0[q] : bi1[q];
        }
        __syncthreads();
        if (tid < 64) {
            int mwi = tid >> 5, mcol = tid & 31;
            float mv[MPRE]; int mi[MPRE];
            #pragma unroll
            for (int q = 0; q < MPRE; ++q) { mv[q] = -3.4e38f; mi[q] = 0x7fffffff; }
            for (int wjj = 0; wjj < 2; ++wjj)
                for (int hh = 0; hh < 2; ++hh)
                    for (int qq = 0; qq < MPRE; ++qq) {
                        float v = mv_s[mwi][mcol][wjj][hh][qq];
                        int  ix = mi_s[mwi][mcol][wjj][hh][qq];
                        if (lex_gt(v, ix, mv[MPRE - 1], mi[MPRE - 1])) {
                            float cv = v; int ci = ix;
                            #pragma unroll
                            for (int p = 0; p < MPRE; ++p) {
                                if (lex_gt(cv, ci, mv[p], mi[p])) {
                                    float tv = mv[p]; mv[p] = cv; cv = tv;
                                    int tx2 = mi[p]; mi[p] = ci; ci = tx2;
                                }
                            }
                        }
                    }
            int i_g = i0 + mwi * 64 + ig * 32 + mcol;
            int* dst = pi_pre + (((size_t)b * N_ + i_g) * JSPLIT + js) * MPRE;
            #pragma unroll
            for (int q = 0; q < MPRE; ++q) dst[q] = mi[q];
        }
    }
}

// ---------------------------------------------------------------------------
// Kernel 5: exact fp32 rerank of the 2*MPRE candidates -> final knn[row][8].
// One wave per row; lane-split over C (4 floats/lane), butterfly reduce.
// ---------------------------------------------------------------------------
__global__ __launch_bounds__(256) void k_rerank(const float* __restrict__ nodes,
                                                const float* __restrict__ sq,
                                                const int* __restrict__ pi_pre,
                                                int* __restrict__ knn) {
    int row  = blockIdx.x * 4 + (threadIdx.x >> 6);   // b*N+i
    int lane = threadIdx.x & 63;
    int b = row / N_;
    const float* Xb = nodes + (size_t)b * N_ * C_;
    float4 xi = *(const float4*)(nodes + (size_t)row * C_ + lane * 4);
    float sqi = sq[row];
    const int* cand = pi_pre + (size_t)row * JSPLIT * MPRE;

    float bd[KNN]; int bj[KNN];
    #pragma unroll
    for (int q = 0; q < KNN; ++q) { bd[q] = 3.4e38f; bj[q] = 0x7fffffff; }

    for (int s = 0; s < JSPLIT * MPRE; ++s) {
        int j = cand[s];
        if ((unsigned)j >= (unsigned)N_) continue;
        float4 xj = *(const float4*)(Xb + (size_t)j * C_ + lane * 4);
        float p = xi.x * xj.x + xi.y * xj.y + xi.z * xj.z + xi.w * xj.w;
        #pragma unroll
        for (int m = 1; m < 64; m <<= 1) p += __shfl_xor(p, m);
        float d2 = sqi + sq[b * N_ + j] - 2.f * p;
        if (lex_lt(d2, j, bd[KNN - 1], bj[KNN - 1])) {
            float cv = d2; int ci = j;
            #pragma unroll
            for (int q = 0; q < KNN; ++q) {
                if (lex_lt(cv, ci, bd[q], bj[q])) {
                    float tv = bd[q]; bd[q] = cv; cv = tv;
                    int tx2 = bj[q]; bj[q] = ci; ci = tx2;
                }
            }
        }
    }
    if (lane == 0) {
        int* kr = knn + (size_t)row * KNN;
        #pragma unroll
        for (int q = 0; q < KNN; ++q) kr[q] = bj[q];
    }
}

// ---------------------------------------------------------------------------
// Kernel 6: aggregate (grid 4-nbrs + 8 knn) mean + residual + LayerNorm(C)
//           + transposed write-out to [B,C,N]
// ---------------------------------------------------------------------------
__global__ __launch_bounds__(256) void k_agg_ln(const float* __restrict__ nodes,
                                                const int* __restrict__ knn,
                                                const float* __restrict__ gamma,
                                                const float* __restrict__ beta,
                                                float* __restrict__ out) {
    __shared__ float ytile[16][C_ + 1];
    __shared__ float red[8];

    int b   = blockIdx.y;
    int i0  = blockIdx.x * 16;
    int tid = threadIdx.x;   // channel c
    const float* Xb = nodes + (size_t)b * N_ * C_;
    float g  = gamma[tid];
    float be = beta[tid];

    for (int ii = 0; ii < 16; ++ii) {
        int i  = i0 + ii;
        int x_ = i % W_;
        int y_ = i / W_;
        float s = 0.f;
        int cnt = KNN;
        if (x_ > 0)      { s += Xb[(size_t)(i - 1)  * C_ + tid]; cnt++; }
        if (x_ < W_ - 1) { s += Xb[(size_t)(i + 1)  * C_ + tid]; cnt++; }
        if (y_ > 0)      { s += Xb[(size_t)(i - W_) * C_ + tid]; cnt++; }
        if (y_ < H_ - 1) { s += Xb[(size_t)(i + W_) * C_ + tid]; cnt++; }
        const int* kr = knn + ((size_t)b * N_ + i) * KNN;
        #pragma unroll
        for (int k = 0; k < KNN; ++k) s += Xb[(size_t)kr[k] * C_ + tid];

        float yv = s / (float)cnt + Xb[(size_t)i * C_ + tid];

        float rx = yv, ry = yv * yv;
        #pragma unroll
        for (int m = 32; m >= 1; m >>= 1) { rx += __shfl_xor(rx, m); ry += __shfl_xor(ry, m); }
        int wid = tid >> 6, lane = tid & 63;
        __syncthreads();
        if (lane == 0) { red[wid * 2] = rx; red[wid * 2 + 1] = ry; }
        __syncthreads();
        float S1 = red[0] + red[2] + red[4] + red[6];
        float S2 = red[1] + red[3] + red[5] + red[7];
        float mu  = S1 * (1.f / C_);
        float var = S2 * (1.f / C_) - mu * mu;
        float inv = rsqrtf(var + 1e-5f);
        ytile[ii][tid] = (yv - mu) * inv * g + be;
    }
    __syncthreads();

    float* op = out + (size_t)b * C_ * N_ + (size_t)tid * N_ + i0;
    float vv[16];
    #pragma unroll
    for (int ii = 0; ii < 16; ++ii) vv[ii] = ytile[ii][tid];
    #pragma unroll
    for (int q = 0; q < 4; ++q) {
        float4 w;
        w.x = vv[q * 4 + 0]; w.y = vv[q * 4 + 1];
        w.z = vv[q * 4 + 2]; w.w = vv[q * 4 + 3];
        *(float4*)&op[q * 4] = w;
    }
}

// ---------------------------------------------------------------------------
extern "C" void kernel_launch(void* const* d_in, const int* in_sizes, int n_in,
                              void* d_out, int out_size, void* d_ws, size_t ws_size,
                              hipStream_t stream) {
    const float* fm    = (const float*)d_in[0];
    const float* gamma = (const float*)d_in[1];
    const float* beta  = (const float*)d_in[2];
    float* out = (float*)d_out;

    char* ws = (char*)d_ws;
    size_t off = 0;
    float* nodes = (float*)(ws + off); off += (size_t)B_ * N_ * C_ * sizeof(float);           // 37.75 MB
    float* sq    = (float*)(ws + off); off += (size_t)B_ * N_ * sizeof(float);                // 0.14 MB
    int*   knn   = (int*)  (ws + off); off += (size_t)B_ * N_ * KNN * sizeof(int);            // 1.18 MB
    unsigned short* Xa = (unsigned short*)(ws + off);
    off += (size_t)B_ * N_ * KA * sizeof(unsigned short);                                     // 21.23 MB
    int* pi_pre = (int*)(ws + off);
    off += (size_t)B_ * N_ * JSPLIT * MPRE * sizeof(int);                                     // 2.95 MB

    k_transpose<<<dim3(N_ / 32, C_ / 32, B_), dim3(32, 8), 0, stream>>>(fm, nodes);
    k_sq<<<dim3(N_ / 256, B_), 256, 0, stream>>>(fm, sq);
    k_convert<<<(B_ * N_ * 36) / 256, 256, 0, stream>>>(nodes, sq, Xa);
    k_knn_mfma<<<dim3(N_ / 128, JSPLIT, B_), 256, 0, stream>>>(Xa, pi_pre);
    k_rerank<<<(B_ * N_) / 4, 256, 0, stream>>>(nodes, sq, pi_pre, knn);
    k_agg_ln<<<dim3(N_ / 16, B_), 256, 0, stream>>>(nodes, knn, gamma, beta, out);
}

// Round 6
// 804.193 us; speedup vs baseline: 3.0708x; 1.1990x over previous
//
#include <hip/hip_runtime.h>

#define B_   16
#define C_   256
#define H_   48
#define W_   48
#define N_   (H_ * W_)   // 2304
#define KNN  8

#define NG   (N_ / 32)   // 72 row-groups per sample
#define NT   17          // K-chunks of 16: 256 data + 16 augment (e1,e2,zeros)
#define FRAG 512         // u16 elements per (g,t) fragment block (64 lanes x 8)
#define MPRE 10          // prefilter depth per j-subset
#define JSPLIT 2

typedef __attribute__((ext_vector_type(8)))  short bf16x8;
typedef __attribute__((ext_vector_type(8)))  unsigned short u16x8;
typedef __attribute__((ext_vector_type(16))) float f32x16;

__device__ __forceinline__ unsigned short f2bf(float f) {
    unsigned int u = __float_as_uint(f);
    u = (u + 0x7FFF + ((u >> 16) & 1)) >> 16;   // RNE
    return (unsigned short)u;
}
__device__ __forceinline__ float bf2f(unsigned short h) {
    return __uint_as_float(((unsigned int)h) << 16);
}
__device__ __forceinline__ bool lex_lt(float v, int i, float bv, int bi) {
    return (v < bv) || (v == bv && i < bi);
}
__device__ __forceinline__ bool lex_gt(float v, int i, float bv, int bi) {
    return (v > bv) || (v == bv && i < bi);
}

// ---------------------------------------------------------------------------
// Kernel 1: transpose [B,C,N] -> [B,N,C]  + emit bf16 MFMA fragments.
// Fragment layout: Xf[b][g][t][lane][8]  (g=n/32, t=k-chunk of 16, 1KB blocks)
//   lane l holds row g*32+(l&31), k = t*16 + (l>>5)*8 + e.
// Each transpose block (n0=32 rows, c0=32 cols) covers g=n0/32, t=2*by,2*by+1:
// waves 0,1 emit one fragment each from the LDS tile (free: data already here).
// ---------------------------------------------------------------------------
__global__ __launch_bounds__(256) void k_transpose(const float* __restrict__ fm,
                                                   float* __restrict__ nodes,
                                                   unsigned short* __restrict__ Xf) {
    __shared__ float tile[32][33];   // [c_local][n_local]
    int b  = blockIdx.z;
    int n0 = blockIdx.x * 32;
    int c0 = blockIdx.y * 32;
    int tx = threadIdx.x, ty = threadIdx.y;
    const float* src = fm + (size_t)b * C_ * N_;
    float* dst = nodes + (size_t)b * N_ * C_;
    #pragma unroll
    for (int cc = 0; cc < 32; cc += 8)
        tile[cc + ty][tx] = src[(size_t)(c0 + cc + ty) * N_ + n0 + tx];
    __syncthreads();
    #pragma unroll
    for (int nn = 0; nn < 32; nn += 8)
        dst[(size_t)(n0 + nn + ty) * C_ + c0 + tx] = tile[tx][nn + ty];

    // fragment emission (waves 0,1)
    int flat = ty * 32 + tx;
    int wv = flat >> 6, lane = flat & 63;
    if (wv < 2) {
        int t   = 2 * blockIdx.y + wv;
        int l31 = lane & 31, lh = lane >> 5;
        u16x8 o;
        #pragma unroll
        for (int e = 0; e < 8; ++e)
            o[e] = f2bf(tile[wv * 16 + lh * 8 + e][l31]);
        unsigned short* df = Xf + (((size_t)b * NG + blockIdx.x) * NT + t) * FRAG + lane * 8;
        *(u16x8*)df = o;
    }
}

// ---------------------------------------------------------------------------
// Kernel 2: sq[b,n] = sum_c fm[b,c,n]^2, and write the t=16 augment fragment:
//   lane (n&31):      {e1, e2, 0...}   (e1+e2 ~= -sq/2, bf16 two-term split)
//   lane (n&31)+32:   {0...}
// ---------------------------------------------------------------------------
__global__ __launch_bounds__(256) void k_sq(const float* __restrict__ fm,
                                            float* __restrict__ sq,
                                            unsigned short* __restrict__ Xf) {
    int b = blockIdx.y;
    int n = blockIdx.x * 256 + threadIdx.x;
    const float* src = fm + (size_t)b * C_ * N_ + n;
    float s = 0.f;
    for (int c = 0; c < C_; ++c) { float v = src[(size_t)c * N_]; s = fmaf(v, v, s); }
    sq[b * N_ + n] = s;

    float sh = -0.5f * s;
    unsigned short e1 = f2bf(sh);
    unsigned short e2 = f2bf(sh - bf2f(e1));
    int g = n >> 5, l = n & 31;
    unsigned short* df = Xf + (((size_t)b * NG + g) * NT + 16) * FRAG + l * 8;
    u16x8 o = (u16x8){0, 0, 0, 0, 0, 0, 0, 0};
    o[0] = e1; o[1] = e2;
    *(u16x8*)df = o;
    u16x8 z = (u16x8){0, 0, 0, 0, 0, 0, 0, 0};
    *(u16x8*)(df + 32 * 8) = z;
}

// ---------------------------------------------------------------------------
// Kernel 3: MFMA prefilter, fragment-layout edition (all loads coalesced).
// Block: 4 waves. wave = (wj = wave>>1, wi = wave&1).
//   i-group gi = i0/32 + wi (resident bfr[16] + const bc), one acc per wave.
//   j-groups: gj = js*36 + jt*2 + wj, jt=0..17 (ascending j per lane).
// S'[j][i] = dot(Xj,Xi) - sqj/2;  lane owns i-col = i0+wi*32+(lane&31),
// 16 j-rows per group via (r&3)+8*(r>>2)+4*(lane>>5). Per-lane top-MPRE,
// then 4-list LDS merge (wj x lh) -> pi_pre[b][i][js][MPRE].
// ---------------------------------------------------------------------------
__global__ __launch_bounds__(256) void k_knn_mfma(const unsigned short* __restrict__ Xf,
                                                  int* __restrict__ pi_pre) {
    __shared__ float mv_s[2][32][2][2][MPRE];   // [wi][col][wj][lh][q]
    __shared__ int   mi_s[2][32][2][2][MPRE];

    int b   = blockIdx.z;
    int i0  = blockIdx.x * 64;
    int js  = blockIdx.y;
    int tid = threadIdx.x;
    int wave = tid >> 6, lane = tid & 63;
    int wi = wave & 1, wj = wave >> 1;
    int l31 = lane & 31, lh = lane >> 5;

    const unsigned short* Xb = Xf + (size_t)b * NG * NT * FRAG;
    int gi = (i0 >> 5) + wi;

    bf16x8 bfr[16];
    const unsigned short* ibase = Xb + (size_t)gi * NT * FRAG + lane * 8;
    #pragma unroll
    for (int t = 0; t < 16; ++t) bfr[t] = *(const bf16x8*)(ibase + t * FRAG);
    short one = (lh == 0) ? (short)0x3F80 : (short)0;
    bf16x8 bc = (bf16x8){one, one, 0, 0, 0, 0, 0, 0};

    int I0 = i0 + wi * 32 + l31;

    float bv[MPRE]; int bi[MPRE];
    #pragma unroll
    for (int q = 0; q < MPRE; ++q) { bv[q] = -3.4e38f; bi[q] = 0x7fffffff; }

    for (int jt = 0; jt < 18; ++jt) {
        int gj = js * (NG / JSPLIT) + jt * 2 + wj;
        const unsigned short* ab = Xb + (size_t)gj * NT * FRAG + lane * 8;

        f32x16 acc;
        #pragma unroll
        for (int r = 0; r < 16; ++r) acc[r] = 0.f;

        #pragma unroll
        for (int t = 0; t < 16; ++t) {
            bf16x8 af = *(const bf16x8*)(ab + t * FRAG);
            acc = __builtin_amdgcn_mfma_f32_32x32x16_bf16(af, bfr[t], acc, 0, 0, 0);
        }
        {
            bf16x8 af = *(const bf16x8*)(ab + 16 * FRAG);
            acc = __builtin_amdgcn_mfma_f32_32x32x16_bf16(af, bc, acc, 0, 0, 0);
        }

        int j0 = gj * 32;
        #pragma unroll
        for (int r = 0; r < 16; ++r) {
            int gjrow = j0 + (r & 3) + 8 * (r >> 2) + 4 * lh;
            float v = (gjrow == I0) ? -3.4e38f : acc[r];
            if (v > bv[MPRE - 1]) {    // strict >: ascending-j stream keeps smaller j on ties
                float cv = v; int ci = gjrow;
                #pragma unroll
                for (int p = 0; p < MPRE; ++p) {
                    if (cv > bv[p]) {
                        float tv = bv[p]; bv[p] = cv; cv = tv;
                        int tx2 = bi[p]; bi[p] = ci; ci = tx2;
                    }
                }
            }
        }
    }

    #pragma unroll
    for (int q = 0; q < MPRE; ++q) {
        mv_s[wi][l31][wj][lh][q] = bv[q];
        mi_s[wi][l31][wj][lh][q] = bi[q];
    }
    __syncthreads();
    if (tid < 64) {
        int mwi = tid >> 5, mcol = tid & 31;
        float mv[MPRE]; int mi[MPRE];
        #pragma unroll
        for (int q = 0; q < MPRE; ++q) { mv[q] = -3.4e38f; mi[q] = 0x7fffffff; }
        for (int wjj = 0; wjj < 2; ++wjj)
            for (int hh = 0; hh < 2; ++hh)
                for (int qq = 0; qq < MPRE; ++qq) {
                    float v = mv_s[mwi][mcol][wjj][hh][qq];
                    int  ix = mi_s[mwi][mcol][wjj][hh][qq];
                    if (lex_gt(v, ix, mv[MPRE - 1], mi[MPRE - 1])) {
                        float cv = v; int ci = ix;
                        #pragma unroll
                        for (int p = 0; p < MPRE; ++p) {
                            if (lex_gt(cv, ci, mv[p], mi[p])) {
                                float tv = mv[p]; mv[p] = cv; cv = tv;
                                int tx2 = mi[p]; mi[p] = ci; ci = tx2;
                            }
                        }
                    }
                }
        int i_g = i0 + mwi * 32 + mcol;
        int* dst = pi_pre + (((size_t)b * N_ + i_g) * JSPLIT + js) * MPRE;
        #pragma unroll
        for (int q = 0; q < MPRE; ++q) dst[q] = mi[q];
    }
}

// ---------------------------------------------------------------------------
// Kernel 4: exact fp32 rerank of the JSPLIT*MPRE candidates -> knn[row][8].
// One wave per row; lane-split over C (4 floats/lane), butterfly reduce.
// ---------------------------------------------------------------------------
__global__ __launch_bounds__(256) void k_rerank(const float* __restrict__ nodes,
                                                const float* __restrict__ sq,
                                                const int* __restrict__ pi_pre,
                                                int* __restrict__ knn) {
    int row  = blockIdx.x * 4 + (threadIdx.x >> 6);   // b*N+i
    int lane = threadIdx.x & 63;
    int b = row / N_;
    const float* Xb = nodes + (size_t)b * N_ * C_;
    float4 xi = *(const float4*)(nodes + (size_t)row * C_ + lane * 4);
    float sqi = sq[row];
    const int* cand = pi_pre + (size_t)row * JSPLIT * MPRE;

    float bd[KNN]; int bj[KNN];
    #pragma unroll
    for (int q = 0; q < KNN; ++q) { bd[q] = 3.4e38f; bj[q] = 0x7fffffff; }

    for (int s = 0; s < JSPLIT * MPRE; ++s) {
        int j = cand[s];
        if ((unsigned)j >= (unsigned)N_) continue;
        float4 xj = *(const float4*)(Xb + (size_t)j * C_ + lane * 4);
        float p = xi.x * xj.x + xi.y * xj.y + xi.z * xj.z + xi.w * xj.w;
        #pragma unroll
        for (int m = 1; m < 64; m <<= 1) p += __shfl_xor(p, m);
        float d2 = sqi + sq[b * N_ + j] - 2.f * p;
        if (lex_lt(d2, j, bd[KNN - 1], bj[KNN - 1])) {
            float cv = d2; int ci = j;
            #pragma unroll
            for (int q = 0; q < KNN; ++q) {
                if (lex_lt(cv, ci, bd[q], bj[q])) {
                    float tv = bd[q]; bd[q] = cv; cv = tv;
                    int tx2 = bj[q]; bj[q] = ci; ci = tx2;
                }
            }
        }
    }
    if (lane == 0) {
        int* kr = knn + (size_t)row * KNN;
        #pragma unroll
        for (int q = 0; q < KNN; ++q) kr[q] = bj[q];
    }
}

// ---------------------------------------------------------------------------
// Kernel 5: aggregate (grid 4-nbrs + 8 knn) mean + residual + LayerNorm(C)
//           + transposed write-out to [B,C,N]
// ---------------------------------------------------------------------------
__global__ __launch_bounds__(256) void k_agg_ln(const float* __restrict__ nodes,
                                                const int* __restrict__ knn,
                                                const float* __restrict__ gamma,
                                                const float* __restrict__ beta,
                                                float* __restrict__ out) {
    __shared__ float ytile[16][C_ + 1];
    __shared__ float red[8];

    int b   = blockIdx.y;
    int i0  = blockIdx.x * 16;
    int tid = threadIdx.x;   // channel c
    const float* Xb = nodes + (size_t)b * N_ * C_;
    float g  = gamma[tid];
    float be = beta[tid];

    for (int ii = 0; ii < 16; ++ii) {
        int i  = i0 + ii;
        int x_ = i % W_;
        int y_ = i / W_;
        float s = 0.f;
        int cnt = KNN;
        if (x_ > 0)      { s += Xb[(size_t)(i - 1)  * C_ + tid]; cnt++; }
        if (x_ < W_ - 1) { s += Xb[(size_t)(i + 1)  * C_ + tid]; cnt++; }
        if (y_ > 0)      { s += Xb[(size_t)(i - W_) * C_ + tid]; cnt++; }
        if (y_ < H_ - 1) { s += Xb[(size_t)(i + W_) * C_ + tid]; cnt++; }
        const int* kr = knn + ((size_t)b * N_ + i) * KNN;
        #pragma unroll
        for (int k = 0; k < KNN; ++k) s += Xb[(size_t)kr[k] * C_ + tid];

        float yv = s / (float)cnt + Xb[(size_t)i * C_ + tid];

        float rx = yv, ry = yv * yv;
        #pragma unroll
        for (int m = 32; m >= 1; m >>= 1) { rx += __shfl_xor(rx, m); ry += __shfl_xor(ry, m); }
        int wid = tid >> 6, lane = tid & 63;
        __syncthreads();
        if (lane == 0) { red[wid * 2] = rx; red[wid * 2 + 1] = ry; }
        __syncthreads();
        float S1 = red[0] + red[2] + red[4] + red[6];
        float S2 = red[1] + red[3] + red[5] + red[7];
        float mu  = S1 * (1.f / C_);
        float var = S2 * (1.f / C_) - mu * mu;
        float inv = rsqrtf(var + 1e-5f);
        ytile[ii][tid] = (yv - mu) * inv * g + be;
    }
    __syncthreads();

    float* op = out + (size_t)b * C_ * N_ + (size_t)tid * N_ + i0;
    float vv[16];
    #pragma unroll
    for (int ii = 0; ii < 16; ++ii) vv[ii] = ytile[ii][tid];
    #pragma unroll
    for (int q = 0; q < 4; ++q) {
        float4 w;
        w.x = vv[q * 4 + 0]; w.y = vv[q * 4 + 1];
        w.z = vv[q * 4 + 2]; w.w = vv[q * 4 + 3];
        *(float4*)&op[q * 4] = w;
    }
}

// ---------------------------------------------------------------------------
extern "C" void kernel_launch(void* const* d_in, const int* in_sizes, int n_in,
                              void* d_out, int out_size, void* d_ws, size_t ws_size,
                              hipStream_t stream) {
    const float* fm    = (const float*)d_in[0];
    const float* gamma = (const float*)d_in[1];
    const float* beta  = (const float*)d_in[2];
    float* out = (float*)d_out;

    char* ws = (char*)d_ws;
    size_t off = 0;
    float* nodes = (float*)(ws + off); off += (size_t)B_ * N_ * C_ * sizeof(float);           // 37.75 MB
    float* sq    = (float*)(ws + off); off += (size_t)B_ * N_ * sizeof(float);                // 0.14 MB
    int*   knn   = (int*)  (ws + off); off += (size_t)B_ * N_ * KNN * sizeof(int);            // 1.18 MB
    unsigned short* Xf = (unsigned short*)(ws + off);
    off += (size_t)B_ * NG * NT * FRAG * sizeof(unsigned short);                              // 20.05 MB
    int* pi_pre = (int*)(ws + off);
    off += (size_t)B_ * N_ * JSPLIT * MPRE * sizeof(int);                                     // 2.95 MB

    k_transpose<<<dim3(N_ / 32, C_ / 32, B_), dim3(32, 8), 0, stream>>>(fm, nodes, Xf);
    k_sq<<<dim3(N_ / 256, B_), 256, 0, stream>>>(fm, sq, Xf);
    k_knn_mfma<<<dim3(N_ / 64, JSPLIT, B_), 256, 0, stream>>>(Xf, pi_pre);
    k_rerank<<<(B_ * N_) / 4, 256, 0, stream>>>(nodes, sq, pi_pre, knn);
    k_agg_ln<<<dim3(N_ / 16, B_), 256, 0, stream>>>(nodes, knn, gamma, beta, out);
}

// Round 7
// 445.414 us; speedup vs baseline: 5.5442x; 1.8055x over previous
//
#include <hip/hip_runtime.h>

#define B_   16
#define C_   256
#define H_   48
#define W_   48
#define N_   (H_ * W_)   // 2304
#define KNN  8

#define NG   (N_ / 32)   // 72 row-groups per sample
#define NT   17          // K-chunks of 16: 256 data + 16 augment (e1,e2,zeros)
#define FRAG 512         // u16 elements per (g,t) fragment block (64 lanes x 8)
#define MPRE 10          // prefilter depth per j-subset
#define JSPLIT 2

typedef __attribute__((ext_vector_type(8)))  short bf16x8;
typedef __attribute__((ext_vector_type(8)))  unsigned short u16x8;
typedef __attribute__((ext_vector_type(16))) float f32x16;

__device__ __forceinline__ unsigned short f2bf(float f) {
    unsigned int u = __float_as_uint(f);
    u = (u + 0x7FFF + ((u >> 16) & 1)) >> 16;   // RNE
    return (unsigned short)u;
}
__device__ __forceinline__ float bf2f(unsigned short h) {
    return __uint_as_float(((unsigned int)h) << 16);
}
__device__ __forceinline__ bool lex_lt(float v, int i, float bv, int bi) {
    return (v < bv) || (v == bv && i < bi);
}
// monotone f32 -> u32 (order-preserving for all non-NaN)
__device__ __forceinline__ unsigned int f2sort(float f) {
    unsigned int u = __float_as_uint(f);
    return u ^ ((unsigned int)((int)u >> 31) | 0x80000000u);
}

// ---------------------------------------------------------------------------
// Kernel 1: transpose [B,C,N] -> [B,N,C]  + emit bf16 MFMA fragments.
// Fragment layout: Xf[b][g][t][lane][8]  (g=n/32, t=k-chunk of 16, 1KB blocks)
//   lane l holds row g*32+(l&31), k = t*16 + (l>>5)*8 + e.
// ---------------------------------------------------------------------------
__global__ __launch_bounds__(256) void k_transpose(const float* __restrict__ fm,
                                                   float* __restrict__ nodes,
                                                   unsigned short* __restrict__ Xf) {
    __shared__ float tile[32][33];   // [c_local][n_local]
    int b  = blockIdx.z;
    int n0 = blockIdx.x * 32;
    int c0 = blockIdx.y * 32;
    int tx = threadIdx.x, ty = threadIdx.y;
    const float* src = fm + (size_t)b * C_ * N_;
    float* dst = nodes + (size_t)b * N_ * C_;
    #pragma unroll
    for (int cc = 0; cc < 32; cc += 8)
        tile[cc + ty][tx] = src[(size_t)(c0 + cc + ty) * N_ + n0 + tx];
    __syncthreads();
    #pragma unroll
    for (int nn = 0; nn < 32; nn += 8)
        dst[(size_t)(n0 + nn + ty) * C_ + c0 + tx] = tile[tx][nn + ty];

    // fragment emission (waves 0,1)
    int flat = ty * 32 + tx;
    int wv = flat >> 6, lane = flat & 63;
    if (wv < 2) {
        int t   = 2 * blockIdx.y + wv;
        int l31 = lane & 31, lh = lane >> 5;
        u16x8 o;
        #pragma unroll
        for (int e = 0; e < 8; ++e)
            o[e] = f2bf(tile[wv * 16 + lh * 8 + e][l31]);
        unsigned short* df = Xf + (((size_t)b * NG + blockIdx.x) * NT + t) * FRAG + lane * 8;
        *(u16x8*)df = o;
    }
}

// ---------------------------------------------------------------------------
// Kernel 2: sq[b,n] = sum_c fm[b,c,n]^2, and write the t=16 augment fragment.
// ---------------------------------------------------------------------------
__global__ __launch_bounds__(256) void k_sq(const float* __restrict__ fm,
                                            float* __restrict__ sq,
                                            unsigned short* __restrict__ Xf) {
    int b = blockIdx.y;
    int n = blockIdx.x * 256 + threadIdx.x;
    const float* src = fm + (size_t)b * C_ * N_ + n;
    float s = 0.f;
    for (int c = 0; c < C_; ++c) { float v = src[(size_t)c * N_]; s = fmaf(v, v, s); }
    sq[b * N_ + n] = s;

    float sh = -0.5f * s;
    unsigned short e1 = f2bf(sh);
    unsigned short e2 = f2bf(sh - bf2f(e1));
    int g = n >> 5, l = n & 31;
    unsigned short* df = Xf + (((size_t)b * NG + g) * NT + 16) * FRAG + l * 8;
    u16x8 o = (u16x8){0, 0, 0, 0, 0, 0, 0, 0};
    o[0] = e1; o[1] = e2;
    *(u16x8*)df = o;
    u16x8 z = (u16x8){0, 0, 0, 0, 0, 0, 0, 0};
    *(u16x8*)(df + 32 * 8) = z;
}

// ---------------------------------------------------------------------------
// Kernel 3: MFMA prefilter with PACKED u32 selection.
// packed = (sortable(S') & 0xFFFFF000) | (4095 - j)   [N=2304 < 4096]
//   unsigned-greater == (larger S', tie -> smaller j).  Top-MPRE kept via a
//   branchless v_max_u32/v_min_u32 insertion chain (no index regs).
// Block: 4 waves (wi = wave&1 -> i-group, wj = wave>>1 -> j-phase).
// ---------------------------------------------------------------------------
__global__ __launch_bounds__(256) void k_knn_mfma(const unsigned short* __restrict__ Xf,
                                                  int* __restrict__ pi_pre) {
    __shared__ unsigned int ms[2][32][2][2][MPRE];   // [wi][col][wj][lh][q]

    int b   = blockIdx.z;
    int i0  = blockIdx.x * 64;
    int js  = blockIdx.y;
    int tid = threadIdx.x;
    int wave = tid >> 6, lane = tid & 63;
    int wi = wave & 1, wj = wave >> 1;
    int l31 = lane & 31, lh = lane >> 5;

    const unsigned short* Xb = Xf + (size_t)b * NG * NT * FRAG;
    int gi = (i0 >> 5) + wi;

    bf16x8 bfr[16];
    const unsigned short* ibase = Xb + (size_t)gi * NT * FRAG + lane * 8;
    #pragma unroll
    for (int t = 0; t < 16; ++t) bfr[t] = *(const bf16x8*)(ibase + t * FRAG);
    short one = (lh == 0) ? (short)0x3F80 : (short)0;
    bf16x8 bc = (bf16x8){one, one, 0, 0, 0, 0, 0, 0};

    int I0 = i0 + wi * 32 + l31;

    unsigned int best[MPRE];
    #pragma unroll
    for (int q = 0; q < MPRE; ++q) best[q] = 0u;

    for (int jt = 0; jt < 18; ++jt) {
        int gj = js * (NG / JSPLIT) + jt * 2 + wj;
        const unsigned short* ab = Xb + (size_t)gj * NT * FRAG + lane * 8;

        f32x16 acc;
        #pragma unroll
        for (int r = 0; r < 16; ++r) acc[r] = 0.f;

        #pragma unroll
        for (int t = 0; t < 16; ++t) {
            bf16x8 af = *(const bf16x8*)(ab + t * FRAG);
            acc = __builtin_amdgcn_mfma_f32_32x32x16_bf16(af, bfr[t], acc, 0, 0, 0);
        }
        {
            bf16x8 af = *(const bf16x8*)(ab + 16 * FRAG);
            acc = __builtin_amdgcn_mfma_f32_32x32x16_bf16(af, bc, acc, 0, 0, 0);
        }

        int j0 = gj * 32;
        int idxbase = 4095 - j0 - 4 * lh;    // idx' = idxbase - cr  (fits 12 bits)
        #pragma unroll
        for (int r = 0; r < 16; ++r) {
            int cr = (r & 3) + 8 * (r >> 2);
            int gjrow = j0 + cr + 4 * lh;
            unsigned int p = (f2sort(acc[r]) & 0xFFFFF000u) | (unsigned int)(idxbase - cr);
            p = (gjrow == I0) ? 0u : p;      // self-exclusion
            #pragma unroll
            for (int q = 0; q < MPRE; ++q) {   // branchless sorted-desc insert
                unsigned int hi = p > best[q] ? p : best[q];
                unsigned int lo = p > best[q] ? best[q] : p;
                best[q] = hi; p = lo;
            }
        }
    }

    // merge the 4 per-wave lists per i-col (wj x lh) -> top-MPRE -> pi_pre
    #pragma unroll
    for (int q = 0; q < MPRE; ++q) ms[wi][l31][wj][lh][q] = best[q];
    __syncthreads();
    if (tid < 64) {
        int mwi = tid >> 5, mcol = tid & 31;
        unsigned int mb[MPRE];
        #pragma unroll
        for (int q = 0; q < MPRE; ++q) mb[q] = 0u;
        for (int wjj = 0; wjj < 2; ++wjj)
            for (int hh = 0; hh < 2; ++hh)
                #pragma unroll
                for (int qq = 0; qq < MPRE; ++qq) {
                    unsigned int p = ms[mwi][mcol][wjj][hh][qq];
                    #pragma unroll
                    for (int q = 0; q < MPRE; ++q) {
                        unsigned int hi = p > mb[q] ? p : mb[q];
                        unsigned int lo = p > mb[q] ? mb[q] : p;
                        mb[q] = hi; p = lo;
                    }
                }
        int i_g = i0 + mwi * 32 + mcol;
        int* dst = pi_pre + (((size_t)b * N_ + i_g) * JSPLIT + js) * MPRE;
        #pragma unroll
        for (int q = 0; q < MPRE; ++q) dst[q] = 4095 - (int)(mb[q] & 0xFFFu);
    }
}

// ---------------------------------------------------------------------------
// Kernel 4: exact fp32 rerank of the JSPLIT*MPRE candidates -> knn[row][8].
// One wave per row; lane-split over C (4 floats/lane), butterfly reduce.
// (Unfilled prefilter slots unpack to j=4095 -> skipped by the bounds check.)
// ---------------------------------------------------------------------------
__global__ __launch_bounds__(256) void k_rerank(const float* __restrict__ nodes,
                                                const float* __restrict__ sq,
                                                const int* __restrict__ pi_pre,
                                                int* __restrict__ knn) {
    int row  = blockIdx.x * 4 + (threadIdx.x >> 6);   // b*N+i
    int lane = threadIdx.x & 63;
    int b = row / N_;
    const float* Xb = nodes + (size_t)b * N_ * C_;
    float4 xi = *(const float4*)(nodes + (size_t)row * C_ + lane * 4);
    float sqi = sq[row];
    const int* cand = pi_pre + (size_t)row * JSPLIT * MPRE;

    float bd[KNN]; int bj[KNN];
    #pragma unroll
    for (int q = 0; q < KNN; ++q) { bd[q] = 3.4e38f; bj[q] = 0x7fffffff; }

    for (int s = 0; s < JSPLIT * MPRE; ++s) {
        int j = cand[s];
        if ((unsigned)j >= (unsigned)N_) continue;
        float4 xj = *(const float4*)(Xb + (size_t)j * C_ + lane * 4);
        float p = xi.x * xj.x + xi.y * xj.y + xi.z * xj.z + xi.w * xj.w;
        #pragma unroll
        for (int m = 1; m < 64; m <<= 1) p += __shfl_xor(p, m);
        float d2 = sqi + sq[b * N_ + j] - 2.f * p;
        if (lex_lt(d2, j, bd[KNN - 1], bj[KNN - 1])) {
            float cv = d2; int ci = j;
            #pragma unroll
            for (int q = 0; q < KNN; ++q) {
                if (lex_lt(cv, ci, bd[q], bj[q])) {
                    float tv = bd[q]; bd[q] = cv; cv = tv;
                    int tx2 = bj[q]; bj[q] = ci; ci = tx2;
                }
            }
        }
    }
    if (lane == 0) {
        int* kr = knn + (size_t)row * KNN;
        #pragma unroll
        for (int q = 0; q < KNN; ++q) kr[q] = bj[q];
    }
}

// ---------------------------------------------------------------------------
// Kernel 5: aggregate (grid 4-nbrs + 8 knn) mean + residual + LayerNorm(C)
//           + transposed write-out to [B,C,N]
// ---------------------------------------------------------------------------
__global__ __launch_bounds__(256) void k_agg_ln(const float* __restrict__ nodes,
                                                const int* __restrict__ knn,
                                                const float* __restrict__ gamma,
                                                const float* __restrict__ beta,
                                                float* __restrict__ out) {
    __shared__ float ytile[16][C_ + 1];
    __shared__ float red[8];

    int b   = blockIdx.y;
    int i0  = blockIdx.x * 16;
    int tid = threadIdx.x;   // channel c
    const float* Xb = nodes + (size_t)b * N_ * C_;
    float g  = gamma[tid];
    float be = beta[tid];

    for (int ii = 0; ii < 16; ++ii) {
        int i  = i0 + ii;
        int x_ = i % W_;
        int y_ = i / W_;
        float s = 0.f;
        int cnt = KNN;
        if (x_ > 0)      { s += Xb[(size_t)(i - 1)  * C_ + tid]; cnt++; }
        if (x_ < W_ - 1) { s += Xb[(size_t)(i + 1)  * C_ + tid]; cnt++; }
        if (y_ > 0)      { s += Xb[(size_t)(i - W_) * C_ + tid]; cnt++; }
        if (y_ < H_ - 1) { s += Xb[(size_t)(i + W_) * C_ + tid]; cnt++; }
        const int* kr = knn + ((size_t)b * N_ + i) * KNN;
        #pragma unroll
        for (int k = 0; k < KNN; ++k) s += Xb[(size_t)kr[k] * C_ + tid];

        float yv = s / (float)cnt + Xb[(size_t)i * C_ + tid];

        float rx = yv, ry = yv * yv;
        #pragma unroll
        for (int m = 32; m >= 1; m >>= 1) { rx += __shfl_xor(rx, m); ry += __shfl_xor(ry, m); }
        int wid = tid >> 6, lane = tid & 63;
        __syncthreads();
        if (lane == 0) { red[wid * 2] = rx; red[wid * 2 + 1] = ry; }
        __syncthreads();
        float S1 = red[0] + red[2] + red[4] + red[6];
        float S2 = red[1] + red[3] + red[5] + red[7];
        float mu  = S1 * (1.f / C_);
        float var = S2 * (1.f / C_) - mu * mu;
        float inv = rsqrtf(var + 1e-5f);
        ytile[ii][tid] = (yv - mu) * inv * g + be;
    }
    __syncthreads();

    float* op = out + (size_t)b * C_ * N_ + (size_t)tid * N_ + i0;
    float vv[16];
    #pragma unroll
    for (int ii = 0; ii < 16; ++ii) vv[ii] = ytile[ii][tid];
    #pragma unroll
    for (int q = 0; q < 4; ++q) {
        float4 w;
        w.x = vv[q * 4 + 0]; w.y = vv[q * 4 + 1];
        w.z = vv[q * 4 + 2]; w.w = vv[q * 4 + 3];
        *(float4*)&op[q * 4] = w;
    }
}

// ---------------------------------------------------------------------------
extern "C" void kernel_launch(void* const* d_in, const int* in_sizes, int n_in,
                              void* d_out, int out_size, void* d_ws, size_t ws_size,
                              hipStream_t stream) {
    const float* fm    = (const float*)d_in[0];
    const float* gamma = (const float*)d_in[1];
    const float* beta  = (const float*)d_in[2];
    float* out = (float*)d_out;

    char* ws = (char*)d_ws;
    size_t off = 0;
    float* nodes = (float*)(ws + off); off += (size_t)B_ * N_ * C_ * sizeof(float);           // 37.75 MB
    float* sq    = (float*)(ws + off); off += (size_t)B_ * N_ * sizeof(float);                // 0.14 MB
    int*   knn   = (int*)  (ws + off); off += (size_t)B_ * N_ * KNN * sizeof(int);            // 1.18 MB
    unsigned short* Xf = (unsigned short*)(ws + off);
    off += (size_t)B_ * NG * NT * FRAG * sizeof(unsigned short);                              // 20.05 MB
    int* pi_pre = (int*)(ws + off);
    off += (size_t)B_ * N_ * JSPLIT * MPRE * sizeof(int);                                     // 2.95 MB

    k_transpose<<<dim3(N_ / 32, C_ / 32, B_), dim3(32, 8), 0, stream>>>(fm, nodes, Xf);
    k_sq<<<dim3(N_ / 256, B_), 256, 0, stream>>>(fm, sq, Xf);
    k_knn_mfma<<<dim3(N_ / 64, JSPLIT, B_), 256, 0, stream>>>(Xf, pi_pre);
    k_rerank<<<(B_ * N_) / 4, 256, 0, stream>>>(nodes, sq, pi_pre, knn);
    k_agg_ln<<<dim3(N_ / 16, B_), 256, 0, stream>>>(nodes, knn, gamma, beta, out);
}

// Round 8
// 384.621 us; speedup vs baseline: 6.4205x; 1.1581x over previous
//
#include <hip/hip_runtime.h>

#define B_   16
#define C_   256
#define H_   48
#define W_   48
#define N_   (H_ * W_)   // 2304
#define KNN  8

#define NG   (N_ / 32)   // 72 row-groups per sample
#define NT   17          // K-chunks of 16: 256 data + 16 augment (e1,e2,zeros)
#define FRAG 512         // u16 elements per (g,t) fragment block (64 lanes x 8)
#define MPRE 10          // prefilter depth per j-subset
#define JSPLIT 2
#define NCAND (JSPLIT * MPRE)   // 20

typedef __attribute__((ext_vector_type(8)))  short bf16x8;
typedef __attribute__((ext_vector_type(8)))  unsigned short u16x8;
typedef __attribute__((ext_vector_type(16))) float f32x16;

__device__ __forceinline__ unsigned short f2bf(float f) {
    unsigned int u = __float_as_uint(f);
    u = (u + 0x7FFF + ((u >> 16) & 1)) >> 16;   // RNE
    return (unsigned short)u;
}
__device__ __forceinline__ float bf2f(unsigned short h) {
    return __uint_as_float(((unsigned int)h) << 16);
}
__device__ __forceinline__ bool lex_lt(float v, int i, float bv, int bi) {
    return (v < bv) || (v == bv && i < bi);
}
// monotone f32 -> u32 (order-preserving for all non-NaN)
__device__ __forceinline__ unsigned int f2sort(float f) {
    unsigned int u = __float_as_uint(f);
    return u ^ ((unsigned int)((int)u >> 31) | 0x80000000u);
}

// ---------------------------------------------------------------------------
// Kernel 1: transpose [B,C,N] -> [B,N,C]  + emit bf16 MFMA fragments.
// Fragment layout: Xf[b][g][t][lane][8]  (g=n/32, t=k-chunk of 16, 1KB blocks)
//   lane l holds row g*32+(l&31), k = t*16 + (l>>5)*8 + e.
// ---------------------------------------------------------------------------
__global__ __launch_bounds__(256) void k_transpose(const float* __restrict__ fm,
                                                   float* __restrict__ nodes,
                                                   unsigned short* __restrict__ Xf) {
    __shared__ float tile[32][33];   // [c_local][n_local]
    int b  = blockIdx.z;
    int n0 = blockIdx.x * 32;
    int c0 = blockIdx.y * 32;
    int tx = threadIdx.x, ty = threadIdx.y;
    const float* src = fm + (size_t)b * C_ * N_;
    float* dst = nodes + (size_t)b * N_ * C_;
    #pragma unroll
    for (int cc = 0; cc < 32; cc += 8)
        tile[cc + ty][tx] = src[(size_t)(c0 + cc + ty) * N_ + n0 + tx];
    __syncthreads();
    #pragma unroll
    for (int nn = 0; nn < 32; nn += 8)
        dst[(size_t)(n0 + nn + ty) * C_ + c0 + tx] = tile[tx][nn + ty];

    // fragment emission (waves 0,1)
    int flat = ty * 32 + tx;
    int wv = flat >> 6, lane = flat & 63;
    if (wv < 2) {
        int t   = 2 * blockIdx.y + wv;
        int l31 = lane & 31, lh = lane >> 5;
        u16x8 o;
        #pragma unroll
        for (int e = 0; e < 8; ++e)
            o[e] = f2bf(tile[wv * 16 + lh * 8 + e][l31]);
        unsigned short* df = Xf + (((size_t)b * NG + blockIdx.x) * NT + t) * FRAG + lane * 8;
        *(u16x8*)df = o;
    }
}

// ---------------------------------------------------------------------------
// Kernel 2: sq[b,n] = sum_c fm[b,c,n]^2, and write the t=16 augment fragment.
// ---------------------------------------------------------------------------
__global__ __launch_bounds__(256) void k_sq(const float* __restrict__ fm,
                                            float* __restrict__ sq,
                                            unsigned short* __restrict__ Xf) {
    int b = blockIdx.y;
    int n = blockIdx.x * 256 + threadIdx.x;
    const float* src = fm + (size_t)b * C_ * N_ + n;
    float s = 0.f;
    for (int c = 0; c < C_; ++c) { float v = src[(size_t)c * N_]; s = fmaf(v, v, s); }
    sq[b * N_ + n] = s;

    float sh = -0.5f * s;
    unsigned short e1 = f2bf(sh);
    unsigned short e2 = f2bf(sh - bf2f(e1));
    int g = n >> 5, l = n & 31;
    unsigned short* df = Xf + (((size_t)b * NG + g) * NT + 16) * FRAG + l * 8;
    u16x8 o = (u16x8){0, 0, 0, 0, 0, 0, 0, 0};
    o[0] = e1; o[1] = e2;
    *(u16x8*)df = o;
    u16x8 z = (u16x8){0, 0, 0, 0, 0, 0, 0, 0};
    *(u16x8*)(df + 32 * 8) = z;
}

// ---------------------------------------------------------------------------
// Kernel 3: MFMA prefilter with PACKED u32 selection.
// packed = (sortable(S') & 0xFFFFF000) | (4095 - j)   [N=2304 < 4096]
// ---------------------------------------------------------------------------
__global__ __launch_bounds__(256) void k_knn_mfma(const unsigned short* __restrict__ Xf,
                                                  int* __restrict__ pi_pre) {
    __shared__ unsigned int ms[2][32][2][2][MPRE];   // [wi][col][wj][lh][q]

    int b   = blockIdx.z;
    int i0  = blockIdx.x * 64;
    int js  = blockIdx.y;
    int tid = threadIdx.x;
    int wave = tid >> 6, lane = tid & 63;
    int wi = wave & 1, wj = wave >> 1;
    int l31 = lane & 31, lh = lane >> 5;

    const unsigned short* Xb = Xf + (size_t)b * NG * NT * FRAG;
    int gi = (i0 >> 5) + wi;

    bf16x8 bfr[16];
    const unsigned short* ibase = Xb + (size_t)gi * NT * FRAG + lane * 8;
    #pragma unroll
    for (int t = 0; t < 16; ++t) bfr[t] = *(const bf16x8*)(ibase + t * FRAG);
    short one = (lh == 0) ? (short)0x3F80 : (short)0;
    bf16x8 bc = (bf16x8){one, one, 0, 0, 0, 0, 0, 0};

    int I0 = i0 + wi * 32 + l31;

    unsigned int best[MPRE];
    #pragma unroll
    for (int q = 0; q < MPRE; ++q) best[q] = 0u;

    for (int jt = 0; jt < 18; ++jt) {
        int gj = js * (NG / JSPLIT) + jt * 2 + wj;
        const unsigned short* ab = Xb + (size_t)gj * NT * FRAG + lane * 8;

        f32x16 acc;
        #pragma unroll
        for (int r = 0; r < 16; ++r) acc[r] = 0.f;

        #pragma unroll
        for (int t = 0; t < 16; ++t) {
            bf16x8 af = *(const bf16x8*)(ab + t * FRAG);
            acc = __builtin_amdgcn_mfma_f32_32x32x16_bf16(af, bfr[t], acc, 0, 0, 0);
        }
        {
            bf16x8 af = *(const bf16x8*)(ab + 16 * FRAG);
            acc = __builtin_amdgcn_mfma_f32_32x32x16_bf16(af, bc, acc, 0, 0, 0);
        }

        int j0 = gj * 32;
        int idxbase = 4095 - j0 - 4 * lh;    // idx' = idxbase - cr  (fits 12 bits)
        #pragma unroll
        for (int r = 0; r < 16; ++r) {
            int cr = (r & 3) + 8 * (r >> 2);
            int gjrow = j0 + cr + 4 * lh;
            unsigned int p = (f2sort(acc[r]) & 0xFFFFF000u) | (unsigned int)(idxbase - cr);
            p = (gjrow == I0) ? 0u : p;      // self-exclusion
            #pragma unroll
            for (int q = 0; q < MPRE; ++q) {   // branchless sorted-desc insert
                unsigned int hi = p > best[q] ? p : best[q];
                unsigned int lo = p > best[q] ? best[q] : p;
                best[q] = hi; p = lo;
            }
        }
    }

    #pragma unroll
    for (int q = 0; q < MPRE; ++q) ms[wi][l31][wj][lh][q] = best[q];
    __syncthreads();
    if (tid < 64) {
        int mwi = tid >> 5, mcol = tid & 31;
        unsigned int mb[MPRE];
        #pragma unroll
        for (int q = 0; q < MPRE; ++q) mb[q] = 0u;
        for (int wjj = 0; wjj < 2; ++wjj)
            for (int hh = 0; hh < 2; ++hh)
                #pragma unroll
                for (int qq = 0; qq < MPRE; ++qq) {
                    unsigned int p = ms[mwi][mcol][wjj][hh][qq];
                    #pragma unroll
                    for (int q = 0; q < MPRE; ++q) {
                        unsigned int hi = p > mb[q] ? p : mb[q];
                        unsigned int lo = p > mb[q] ? mb[q] : p;
                        mb[q] = hi; p = lo;
                    }
                }
        int i_g = i0 + mwi * 32 + mcol;
        int* dst = pi_pre + (((size_t)b * N_ + i_g) * JSPLIT + js) * MPRE;
        #pragma unroll
        for (int q = 0; q < MPRE; ++q) dst[q] = 4095 - (int)(mb[q] & 0xFFFu);
    }
}

// ---------------------------------------------------------------------------
// Kernel 4: exact fp32 rerank, group-parallel edition.
// Wave per row; 4 groups of 16 lanes; group g computes candidate it*4+g's
// full 256-ch dot (4 float4/lane passes, 4-step 16-lane butterfly).
// d2 staged in per-wave LDS (same-wave RAW, no barrier), then all lanes do
// the uniform lex (value,index) insertion; lane 0 writes.
// ---------------------------------------------------------------------------
__global__ __launch_bounds__(256) void k_rerank(const float* __restrict__ nodes,
                                                const float* __restrict__ sq,
                                                const int* __restrict__ pi_pre,
                                                int* __restrict__ knn) {
    __shared__ float d2s[4][NCAND];
    __shared__ int   jss[4][NCAND];

    int wv   = threadIdx.x >> 6;
    int lane = threadIdx.x & 63;
    int row  = blockIdx.x * 4 + wv;    // b*N+i
    int g = lane >> 4, m = lane & 15;
    int b = row / N_;
    const float* Xb = nodes + (size_t)b * N_ * C_;
    const float* xi = nodes + (size_t)row * C_;

    float4 xiv[4];
    #pragma unroll
    for (int p = 0; p < 4; ++p) xiv[p] = *(const float4*)&xi[p * 64 + m * 4];
    float sqi = sq[row];
    const int* cand = pi_pre + (size_t)row * NCAND;

    for (int it = 0; it < 5; ++it) {
        int c = it * 4 + g;
        int j = cand[c];
        bool valid = (unsigned)j < (unsigned)N_;
        int jc = valid ? j : 0;
        const float* xj = Xb + (size_t)jc * C_;
        float p = 0.f;
        #pragma unroll
        for (int pp = 0; pp < 4; ++pp) {
            float4 v = *(const float4*)&xj[pp * 64 + m * 4];
            p = fmaf(xiv[pp].x, v.x, p);
            p = fmaf(xiv[pp].y, v.y, p);
            p = fmaf(xiv[pp].z, v.z, p);
            p = fmaf(xiv[pp].w, v.w, p);
        }
        p += __shfl_xor(p, 1);
        p += __shfl_xor(p, 2);
        p += __shfl_xor(p, 4);
        p += __shfl_xor(p, 8);
        if (m == 0) {
            float d2 = valid ? (sqi + sq[b * N_ + jc] - 2.f * p) : 3.4e38f;
            d2s[wv][c] = d2;
            jss[wv][c] = valid ? j : 0x7fffffff;
        }
    }

    // uniform insertion across all lanes (same-wave LDS, no barrier needed)
    float bd[KNN]; int bj[KNN];
    #pragma unroll
    for (int q = 0; q < KNN; ++q) { bd[q] = 3.4e38f; bj[q] = 0x7fffffff; }
    for (int s = 0; s < NCAND; ++s) {
        float v = d2s[wv][s]; int jx = jss[wv][s];
        if (lex_lt(v, jx, bd[KNN - 1], bj[KNN - 1])) {
            float cv = v; int ci = jx;
            #pragma unroll
            for (int q = 0; q < KNN; ++q) {
                if (lex_lt(cv, ci, bd[q], bj[q])) {
                    float tv = bd[q]; bd[q] = cv; cv = tv;
                    int tx2 = bj[q]; bj[q] = ci; ci = tx2;
                }
            }
        }
    }
    if (lane == 0) {
        int* kr = knn + (size_t)row * KNN;
        #pragma unroll
        for (int q = 0; q < KNN; ++q) kr[q] = bj[q];
    }
}

// ---------------------------------------------------------------------------
// Kernel 5: aggregate + residual + LayerNorm, wave-per-row (barrier-free LN).
// 4 waves x 4 rows = 16 rows/block; lane owns channels 4*lane..4*lane+3;
// gathers coalesced (1KB/row); mean/var via 64-lane butterfly; single
// syncthreads before the transposed write-out (same pattern as before).
// ---------------------------------------------------------------------------
__global__ __launch_bounds__(256) void k_agg_ln(const float* __restrict__ nodes,
                                                const int* __restrict__ knn,
                                                const float* __restrict__ gamma,
                                                const float* __restrict__ beta,
                                                float* __restrict__ out) {
    __shared__ float ytile[16][C_ + 1];

    int b   = blockIdx.y;
    int i0  = blockIdx.x * 16;
    int tid = threadIdx.x;
    int wv = tid >> 6, lane = tid & 63;
    const float* Xb = nodes + (size_t)b * N_ * C_;

    float4 g4 = *(const float4*)&gamma[lane * 4];
    float4 b4 = *(const float4*)&beta[lane * 4];

    for (int rr = 0; rr < 4; ++rr) {
        int ii = wv * 4 + rr;
        int i  = i0 + ii;
        int x_ = i % W_;
        int y_ = i / W_;
        float s0 = 0.f, s1 = 0.f, s2 = 0.f, s3 = 0.f;
        int cnt = KNN;

        #define ADDROW(J) { float4 v = *(const float4*)&Xb[(size_t)(J) * C_ + lane * 4]; \
                            s0 += v.x; s1 += v.y; s2 += v.z; s3 += v.w; }
        if (x_ > 0)      { ADDROW(i - 1);  cnt++; }
        if (x_ < W_ - 1) { ADDROW(i + 1);  cnt++; }
        if (y_ > 0)      { ADDROW(i - W_); cnt++; }
        if (y_ < H_ - 1) { ADDROW(i + W_); cnt++; }
        const int* kr = knn + ((size_t)b * N_ + i) * KNN;
        #pragma unroll
        for (int k = 0; k < KNN; ++k) ADDROW(kr[k]);
        #undef ADDROW

        float4 xi = *(const float4*)&Xb[(size_t)i * C_ + lane * 4];
        float ic = 1.f / (float)cnt;
        float y0 = s0 * ic + xi.x;
        float y1 = s1 * ic + xi.y;
        float y2 = s2 * ic + xi.z;
        float y3 = s3 * ic + xi.w;

        float rx = y0 + y1 + y2 + y3;
        float ry = y0 * y0 + y1 * y1 + y2 * y2 + y3 * y3;
        #pragma unroll
        for (int mm = 1; mm < 64; mm <<= 1) {
            rx += __shfl_xor(rx, mm);
            ry += __shfl_xor(ry, mm);
        }
        float mu  = rx * (1.f / C_);
        float var = ry * (1.f / C_) - mu * mu;
        float inv = rsqrtf(var + 1e-5f);

        ytile[ii][lane * 4 + 0] = (y0 - mu) * inv * g4.x + b4.x;
        ytile[ii][lane * 4 + 1] = (y1 - mu) * inv * g4.y + b4.y;
        ytile[ii][lane * 4 + 2] = (y2 - mu) * inv * g4.z + b4.z;
        ytile[ii][lane * 4 + 3] = (y3 - mu) * inv * g4.w + b4.w;
    }
    __syncthreads();

    float* op = out + (size_t)b * C_ * N_ + (size_t)tid * N_ + i0;
    float vv[16];
    #pragma unroll
    for (int ii = 0; ii < 16; ++ii) vv[ii] = ytile[ii][tid];
    #pragma unroll
    for (int q = 0; q < 4; ++q) {
        float4 w;
        w.x = vv[q * 4 + 0]; w.y = vv[q * 4 + 1];
        w.z = vv[q * 4 + 2]; w.w = vv[q * 4 + 3];
        *(float4*)&op[q * 4] = w;
    }
}

// ---------------------------------------------------------------------------
extern "C" void kernel_launch(void* const* d_in, const int* in_sizes, int n_in,
                              void* d_out, int out_size, void* d_ws, size_t ws_size,
                              hipStream_t stream) {
    const float* fm    = (const float*)d_in[0];
    const float* gamma = (const float*)d_in[1];
    const float* beta  = (const float*)d_in[2];
    float* out = (float*)d_out;

    char* ws = (char*)d_ws;
    size_t off = 0;
    float* nodes = (float*)(ws + off); off += (size_t)B_ * N_ * C_ * sizeof(float);           // 37.75 MB
    float* sq    = (float*)(ws + off); off += (size_t)B_ * N_ * sizeof(float);                // 0.14 MB
    int*   knn   = (int*)  (ws + off); off += (size_t)B_ * N_ * KNN * sizeof(int);            // 1.18 MB
    unsigned short* Xf = (unsigned short*)(ws + off);
    off += (size_t)B_ * NG * NT * FRAG * sizeof(unsigned short);                              // 20.05 MB
    int* pi_pre = (int*)(ws + off);
    off += (size_t)B_ * N_ * NCAND * sizeof(int);                                             // 2.95 MB

    k_transpose<<<dim3(N_ / 32, C_ / 32, B_), dim3(32, 8), 0, stream>>>(fm, nodes, Xf);
    k_sq<<<dim3(N_ / 256, B_), 256, 0, stream>>>(fm, sq, Xf);
    k_knn_mfma<<<dim3(N_ / 64, JSPLIT, B_), 256, 0, stream>>>(Xf, pi_pre);
    k_rerank<<<(B_ * N_) / 4, 256, 0, stream>>>(nodes, sq, pi_pre, knn);
    k_agg_ln<<<dim3(N_ / 16, B_), 256, 0, stream>>>(nodes, knn, gamma, beta, out);
}

// Round 10
// 345.862 us; speedup vs baseline: 7.1401x; 1.1121x over previous
//
#include <hip/hip_runtime.h>

#define B_   16
#define C_   256
#define H_   48
#define W_   48
#define N_   (H_ * W_)   // 2304
#define KNN  8

#define NG   (N_ / 32)   // 72 row-groups per sample
#define NT   17          // K-chunks of 16: 256 data + 16 augment (e1,e2,zeros)
#define FRAG 512         // u16 elements per (g,t) fragment block (64 lanes x 8)
#define MPRE 10          // prefilter depth per (wave,lh) subset
#define NCAND 20         // merged candidate union per row

typedef __attribute__((ext_vector_type(8)))  short bf16x8;
typedef __attribute__((ext_vector_type(8)))  unsigned short u16x8;
typedef __attribute__((ext_vector_type(16))) float f32x16;

__device__ __forceinline__ unsigned short f2bf(float f) {
    unsigned int u = __float_as_uint(f);
    u = (u + 0x7FFF + ((u >> 16) & 1)) >> 16;   // RNE
    return (unsigned short)u;
}
__device__ __forceinline__ float bf2f(unsigned short h) {
    return __uint_as_float(((unsigned int)h) << 16);
}
__device__ __forceinline__ bool lex_lt(float v, int i, float bv, int bi) {
    return (v < bv) || (v == bv && i < bi);
}
// monotone f32 -> u32 (order-preserving for all non-NaN)
__device__ __forceinline__ unsigned int f2sort(float f) {
    unsigned int u = __float_as_uint(f);
    return u ^ ((unsigned int)((int)u >> 31) | 0x80000000u);
}

// ---------------------------------------------------------------------------
// Kernel 1: transpose [B,C,N] -> [B,N,C]  + emit bf16 MFMA fragments.
// Fragment layout: Xf[b][g][t][lane][8]  (g=n/32, t=k-chunk of 16, 1KB blocks)
//   lane l holds row g*32+(l&31), k = t*16 + (l>>5)*8 + e.
// ---------------------------------------------------------------------------
__global__ __launch_bounds__(256) void k_transpose(const float* __restrict__ fm,
                                                   float* __restrict__ nodes,
                                                   unsigned short* __restrict__ Xf) {
    __shared__ float tile[32][33];   // [c_local][n_local]
    int b  = blockIdx.z;
    int n0 = blockIdx.x * 32;
    int c0 = blockIdx.y * 32;
    int tx = threadIdx.x, ty = threadIdx.y;
    const float* src = fm + (size_t)b * C_ * N_;
    float* dst = nodes + (size_t)b * N_ * C_;
    #pragma unroll
    for (int cc = 0; cc < 32; cc += 8)
        tile[cc + ty][tx] = src[(size_t)(c0 + cc + ty) * N_ + n0 + tx];
    __syncthreads();
    #pragma unroll
    for (int nn = 0; nn < 32; nn += 8)
        dst[(size_t)(n0 + nn + ty) * C_ + c0 + tx] = tile[tx][nn + ty];

    // fragment emission (waves 0,1)
    int flat = ty * 32 + tx;
    int wv = flat >> 6, lane = flat & 63;
    if (wv < 2) {
        int t   = 2 * blockIdx.y + wv;
        int l31 = lane & 31, lh = lane >> 5;
        u16x8 o;
        #pragma unroll
        for (int e = 0; e < 8; ++e)
            o[e] = f2bf(tile[wv * 16 + lh * 8 + e][l31]);
        unsigned short* df = Xf + (((size_t)b * NG + blockIdx.x) * NT + t) * FRAG + lane * 8;
        *(u16x8*)df = o;
    }
}

// ---------------------------------------------------------------------------
// Kernel 2: sq[b,n] = sum_c fm[b,c,n]^2, and write the t=16 augment fragment.
// ---------------------------------------------------------------------------
__global__ __launch_bounds__(256) void k_sq(const float* __restrict__ fm,
                                            float* __restrict__ sq,
                                            unsigned short* __restrict__ Xf) {
    int b = blockIdx.y;
    int n = blockIdx.x * 256 + threadIdx.x;
    const float* src = fm + (size_t)b * C_ * N_ + n;
    float s = 0.f;
    for (int c = 0; c < C_; ++c) { float v = src[(size_t)c * N_]; s = fmaf(v, v, s); }
    sq[b * N_ + n] = s;

    float sh = -0.5f * s;
    unsigned short e1 = f2bf(sh);
    unsigned short e2 = f2bf(sh - bf2f(e1));
    int g = n >> 5, l = n & 31;
    unsigned short* df = Xf + (((size_t)b * NG + g) * NT + 16) * FRAG + l * 8;
    u16x8 o = (u16x8){0, 0, 0, 0, 0, 0, 0, 0};
    o[0] = e1; o[1] = e2;
    *(u16x8*)df = o;
    u16x8 z = (u16x8){0, 0, 0, 0, 0, 0, 0, 0};
    *(u16x8*)(df + 32 * 8) = z;
}

// ---------------------------------------------------------------------------
// Kernel 3: MFMA prefilter, 8-wave full-j edition with XCD-aware swizzle.
// Grid: 576 1D blocks; wgid = (bid&7)*72 + bid>>3 clusters each b's 36
// blocks on one XCD (per-XCD L2 working set ~2.5 MB of Xf).
// Waves: wi = wave&1 (i-group of 32), wj = wave>>1 (j-phase of 4).
// Per-lane stream: gj = jt*4+wj (18 tiles x 16 rows = 288 candidates).
// packed = (sortable(S') & 0xFFFFF000) | (4095 - j); branchless top-MPRE.
// lh merge: SNAPSHOT partner list via shfl FIRST, then insert (round-9 bug:
// in-place shfl-while-inserting corrupts both lanes' lists).
// Final: 4 wj-lists x 10 -> top-20 union -> pi_pre[row][20].
// NOTE: plain launch_bounds, no min-occupancy arg (round-3 spill lesson).
// ---------------------------------------------------------------------------
__global__ __launch_bounds__(512) void k_knn_mfma(const unsigned short* __restrict__ Xf,
                                                  int* __restrict__ pi_pre) {
    __shared__ unsigned int ms[2][4][32][MPRE];   // [wi][wj][col][q] = 10 KB

    int bid  = blockIdx.x;                        // 576 = 8 * 72
    int wgid = (bid & 7) * 72 + (bid >> 3);       // bijective XCD swizzle
    int b    = wgid / 36;
    int i0   = (wgid % 36) * 64;

    int tid = threadIdx.x;
    int wave = tid >> 6, lane = tid & 63;
    int wi = wave & 1, wj = wave >> 1;            // wj 0..3
    int l31 = lane & 31, lh = lane >> 5;

    const unsigned short* Xb = Xf + (size_t)b * NG * NT * FRAG;
    int gi = (i0 >> 5) + wi;

    bf16x8 bfr[16];
    const unsigned short* ibase = Xb + (size_t)gi * NT * FRAG + lane * 8;
    #pragma unroll
    for (int t = 0; t < 16; ++t) bfr[t] = *(const bf16x8*)(ibase + t * FRAG);
    short one = (lh == 0) ? (short)0x3F80 : (short)0;
    bf16x8 bc = (bf16x8){one, one, 0, 0, 0, 0, 0, 0};

    int I0 = i0 + wi * 32 + l31;

    unsigned int best[MPRE];
    #pragma unroll
    for (int q = 0; q < MPRE; ++q) best[q] = 0u;

    for (int jt = 0; jt < 18; ++jt) {
        int gj = jt * 4 + wj;                     // covers 0..71 across waves
        const unsigned short* ab = Xb + (size_t)gj * NT * FRAG + lane * 8;

        f32x16 acc;
        #pragma unroll
        for (int r = 0; r < 16; ++r) acc[r] = 0.f;

        #pragma unroll
        for (int t = 0; t < 16; ++t) {
            bf16x8 af = *(const bf16x8*)(ab + t * FRAG);
            acc = __builtin_amdgcn_mfma_f32_32x32x16_bf16(af, bfr[t], acc, 0, 0, 0);
        }
        {
            bf16x8 af = *(const bf16x8*)(ab + 16 * FRAG);
            acc = __builtin_amdgcn_mfma_f32_32x32x16_bf16(af, bc, acc, 0, 0, 0);
        }

        int j0 = gj * 32;
        int idxbase = 4095 - j0 - 4 * lh;         // idx' = idxbase - cr (12 bits)
        #pragma unroll
        for (int r = 0; r < 16; ++r) {
            int cr = (r & 3) + 8 * (r >> 2);
            int gjrow = j0 + cr + 4 * lh;
            unsigned int p = (f2sort(acc[r]) & 0xFFFFF000u) | (unsigned int)(idxbase - cr);
            p = (gjrow == I0) ? 0u : p;           // self-exclusion
            #pragma unroll
            for (int q = 0; q < MPRE; ++q) {      // branchless sorted-desc insert
                unsigned int hi = p > best[q] ? p : best[q];
                unsigned int lo = p > best[q] ? best[q] : p;
                best[q] = hi; p = lo;
            }
        }
    }

    // in-wave lh merge: snapshot partner's ORIGINAL list first, then insert.
    {
        unsigned int part[MPRE];
        #pragma unroll
        for (int q = 0; q < MPRE; ++q)
            part[q] = (unsigned int)__shfl_xor((int)best[q], 32);
        #pragma unroll
        for (int q = 0; q < MPRE; ++q) {
            unsigned int p = part[q];
            #pragma unroll
            for (int s = 0; s < MPRE; ++s) {
                unsigned int hi = p > best[s] ? p : best[s];
                unsigned int lo = p > best[s] ? best[s] : p;
                best[s] = hi; p = lo;
            }
        }
    }
    if (lh == 0) {
        #pragma unroll
        for (int q = 0; q < MPRE; ++q) ms[wi][wj][l31][q] = best[q];
    }
    __syncthreads();

    // final merge: 64 threads, one i-col each; 4 wj-lists x 10 -> top-20
    if (tid < 64) {
        int mwi = tid >> 5, mcol = tid & 31;
        unsigned int mb[NCAND];
        #pragma unroll
        for (int q = 0; q < NCAND; ++q) mb[q] = 0u;
        for (int wjj = 0; wjj < 4; ++wjj) {
            #pragma unroll
            for (int qq = 0; qq < MPRE; ++qq) {
                unsigned int p = ms[mwi][wjj][mcol][qq];
                #pragma unroll
                for (int q = 0; q < NCAND; ++q) {
                    unsigned int hi = p > mb[q] ? p : mb[q];
                    unsigned int lo = p > mb[q] ? mb[q] : p;
                    mb[q] = hi; p = lo;
                }
            }
        }
        int i_g = i0 + tid;                       // tid == mwi*32 + mcol
        int* dst = pi_pre + ((size_t)b * N_ + i_g) * NCAND;
        #pragma unroll
        for (int q = 0; q < NCAND; ++q) dst[q] = 4095 - (int)(mb[q] & 0xFFFu);
    }
}

// ---------------------------------------------------------------------------
// Kernel 4: exact fp32 rerank, group-parallel (20 candidates -> top-8).
// Wave per row; 4 groups of 16 lanes; group g computes candidate it*4+g's
// full 256-ch dot (4 float4/lane, 4-step 16-lane butterfly); d2 staged in
// per-wave LDS (same-wave RAW, no barrier), uniform lex insertion, lane 0
// writes. Unfilled slots unpack to j=4095 -> skipped.
// ---------------------------------------------------------------------------
__global__ __launch_bounds__(256) void k_rerank(const float* __restrict__ nodes,
                                                const float* __restrict__ sq,
                                                const int* __restrict__ pi_pre,
                                                int* __restrict__ knn) {
    __shared__ float d2s[4][NCAND];
    __shared__ int   jss[4][NCAND];

    int wv   = threadIdx.x >> 6;
    int lane = threadIdx.x & 63;
    int row  = blockIdx.x * 4 + wv;    // b*N+i
    int g = lane >> 4, m = lane & 15;
    int b = row / N_;
    const float* Xb = nodes + (size_t)b * N_ * C_;
    const float* xi = nodes + (size_t)row * C_;

    float4 xiv[4];
    #pragma unroll
    for (int p = 0; p < 4; ++p) xiv[p] = *(const float4*)&xi[p * 64 + m * 4];
    float sqi = sq[row];
    const int* cand = pi_pre + (size_t)row * NCAND;

    for (int it = 0; it < 5; ++it) {
        int c = it * 4 + g;
        int j = cand[c];
        bool valid = (unsigned)j < (unsigned)N_;
        int jc = valid ? j : 0;
        const float* xj = Xb + (size_t)jc * C_;
        float p = 0.f;
        #pragma unroll
        for (int pp = 0; pp < 4; ++pp) {
            float4 v = *(const float4*)&xj[pp * 64 + m * 4];
            p = fmaf(xiv[pp].x, v.x, p);
            p = fmaf(xiv[pp].y, v.y, p);
            p = fmaf(xiv[pp].z, v.z, p);
            p = fmaf(xiv[pp].w, v.w, p);
        }
        p += __shfl_xor(p, 1);
        p += __shfl_xor(p, 2);
        p += __shfl_xor(p, 4);
        p += __shfl_xor(p, 8);
        if (m == 0) {
            float d2 = valid ? (sqi + sq[b * N_ + jc] - 2.f * p) : 3.4e38f;
            d2s[wv][c] = d2;
            jss[wv][c] = valid ? j : 0x7fffffff;
        }
    }

    float bd[KNN]; int bj[KNN];
    #pragma unroll
    for (int q = 0; q < KNN; ++q) { bd[q] = 3.4e38f; bj[q] = 0x7fffffff; }
    for (int s = 0; s < NCAND; ++s) {
        float v = d2s[wv][s]; int jx = jss[wv][s];
        if (lex_lt(v, jx, bd[KNN - 1], bj[KNN - 1])) {
            float cv = v; int ci = jx;
            #pragma unroll
            for (int q = 0; q < KNN; ++q) {
                if (lex_lt(cv, ci, bd[q], bj[q])) {
                    float tv = bd[q]; bd[q] = cv; cv = tv;
                    int tx2 = bj[q]; bj[q] = ci; ci = tx2;
                }
            }
        }
    }
    if (lane == 0) {
        int* kr = knn + (size_t)row * KNN;
        #pragma unroll
        for (int q = 0; q < KNN; ++q) kr[q] = bj[q];
    }
}

// ---------------------------------------------------------------------------
// Kernel 5: aggregate + residual + LayerNorm, wave-per-row (barrier-free LN).
// ---------------------------------------------------------------------------
__global__ __launch_bounds__(256) void k_agg_ln(const float* __restrict__ nodes,
                                                const int* __restrict__ knn,
                                                const float* __restrict__ gamma,
                                                const float* __restrict__ beta,
                                                float* __restrict__ out) {
    __shared__ float ytile[16][C_ + 1];

    int b   = blockIdx.y;
    int i0  = blockIdx.x * 16;
    int tid = threadIdx.x;
    int wv = tid >> 6, lane = tid & 63;
    const float* Xb = nodes + (size_t)b * N_ * C_;

    float4 g4 = *(const float4*)&gamma[lane * 4];
    float4 b4 = *(const float4*)&beta[lane * 4];

    for (int rr = 0; rr < 4; ++rr) {
        int ii = wv * 4 + rr;
        int i  = i0 + ii;
        int x_ = i % W_;
        int y_ = i / W_;
        float s0 = 0.f, s1 = 0.f, s2 = 0.f, s3 = 0.f;
        int cnt = KNN;

        #define ADDROW(J) { float4 v = *(const float4*)&Xb[(size_t)(J) * C_ + lane * 4]; \
                            s0 += v.x; s1 += v.y; s2 += v.z; s3 += v.w; }
        if (x_ > 0)      { ADDROW(i - 1);  cnt++; }
        if (x_ < W_ - 1) { ADDROW(i + 1);  cnt++; }
        if (y_ > 0)      { ADDROW(i - W_); cnt++; }
        if (y_ < H_ - 1) { ADDROW(i + W_); cnt++; }
        const int* kr = knn + ((size_t)b * N_ + i) * KNN;
        #pragma unroll
        for (int k = 0; k < KNN; ++k) ADDROW(kr[k]);
        #undef ADDROW

        float4 xi = *(const float4*)&Xb[(size_t)i * C_ + lane * 4];
        float ic = 1.f / (float)cnt;
        float y0 = s0 * ic + xi.x;
        float y1 = s1 * ic + xi.y;
        float y2 = s2 * ic + xi.z;
        float y3 = s3 * ic + xi.w;

        float rx = y0 + y1 + y2 + y3;
        float ry = y0 * y0 + y1 * y1 + y2 * y2 + y3 * y3;
        #pragma unroll
        for (int mm = 1; mm < 64; mm <<= 1) {
            rx += __shfl_xor(rx, mm);
            ry += __shfl_xor(ry, mm);
        }
        float mu  = rx * (1.f / C_);
        float var = ry * (1.f / C_) - mu * mu;
        float inv = rsqrtf(var + 1e-5f);

        ytile[ii][lane * 4 + 0] = (y0 - mu) * inv * g4.x + b4.x;
        ytile[ii][lane * 4 + 1] = (y1 - mu) * inv * g4.y + b4.y;
        ytile[ii][lane * 4 + 2] = (y2 - mu) * inv * g4.z + b4.z;
        ytile[ii][lane * 4 + 3] = (y3 - mu) * inv * g4.w + b4.w;
    }
    __syncthreads();

    float* op = out + (size_t)b * C_ * N_ + (size_t)tid * N_ + i0;
    float vv[16];
    #pragma unroll
    for (int ii = 0; ii < 16; ++ii) vv[ii] = ytile[ii][tid];
    #pragma unroll
    for (int q = 0; q < 4; ++q) {
        float4 w;
        w.x = vv[q * 4 + 0]; w.y = vv[q * 4 + 1];
        w.z = vv[q * 4 + 2]; w.w = vv[q * 4 + 3];
        *(float4*)&op[q * 4] = w;
    }
}

// ---------------------------------------------------------------------------
extern "C" void kernel_launch(void* const* d_in, const int* in_sizes, int n_in,
                              void* d_out, int out_size, void* d_ws, size_t ws_size,
                              hipStream_t stream) {
    const float* fm    = (const float*)d_in[0];
    const float* gamma = (const float*)d_in[1];
    const float* beta  = (const float*)d_in[2];
    float* out = (float*)d_out;

    char* ws = (char*)d_ws;
    size_t off = 0;
    float* nodes = (float*)(ws + off); off += (size_t)B_ * N_ * C_ * sizeof(float);           // 37.75 MB
    float* sq    = (float*)(ws + off); off += (size_t)B_ * N_ * sizeof(float);                // 0.14 MB
    int*   knn   = (int*)  (ws + off); off += (size_t)B_ * N_ * KNN * sizeof(int);            // 1.18 MB
    unsigned short* Xf = (unsigned short*)(ws + off);
    off += (size_t)B_ * NG * NT * FRAG * sizeof(unsigned short);                              // 20.05 MB
    int* pi_pre = (int*)(ws + off);
    off += (size_t)B_ * N_ * NCAND * sizeof(int);                                             // 2.95 MB

    k_transpose<<<dim3(N_ / 32, C_ / 32, B_), dim3(32, 8), 0, stream>>>(fm, nodes, Xf);
    k_sq<<<dim3(N_ / 256, B_), 256, 0, stream>>>(fm, sq, Xf);
    k_knn_mfma<<<(B_ * N_) / 64, 512, 0, stream>>>(Xf, pi_pre);
    k_rerank<<<(B_ * N_) / 4, 256, 0, stream>>>(nodes, sq, pi_pre, knn);
    k_agg_ln<<<dim3(N_ / 16, B_), 256, 0, stream>>>(nodes, knn, gamma, beta, out);
}